// Round 1
// baseline (2343.835 us; speedup 1.0000x reference)
//
#include <hip/hip_runtime.h>
#include <math.h>

#define N_ 4
#define T_ 8
#define C_ 512
#define H_ 14
#define W_ 14
#define HEADS_ 8
#define D_ 64
#define HW_ 196
#define S_ 1568
#define P_TOT 6272
#define NEG_ (-4294967295.0f)
#define EPS_ 1e-8f

// ---------------------------------------------------------------------------
// Projection GEMM: Y[p, o] = relu( sum_c X[p, c] * W[o, c] + b[o] )
// X is (N,T,C,H,W); logical row p = n*S + (t*196 + hw), channel stride = 196.
// Output written in head-split layout: out[(head*N + n)*S + s][d], o = head*64+d.
// ---------------------------------------------------------------------------
__global__ __launch_bounds__(256) void proj_kernel(
    const float* __restrict__ X, const float* __restrict__ Wm,
    const float* __restrict__ bias, float* __restrict__ out)
{
    __shared__ float Xs[64][65];
    __shared__ float Ws[64][65];
    const int tid = threadIdx.x;
    const int p0 = blockIdx.x * 64;
    const int o0 = blockIdx.y * 64;

    const int tr = tid >> 4, tc = tid & 15;

    // loader mapping: position ip (0..63) fixed per thread, channel j = jb + 4k
    const int ip = tid & 63;
    const int jb = tid >> 6;
    {
        // nothing
    }
    const int p = p0 + ip;
    const int n = p / S_;
    const int s = p - n * S_;
    const int t = s / HW_;
    const int hw = s - t * HW_;
    const long xbase = (long)((n * T_ + t) * C_) * HW_ + hw;

    const int cl = tid & 63;
    const int ob = tid >> 6;

    float acc[4][4] = {};
    for (int k0 = 0; k0 < C_; k0 += 64) {
        #pragma unroll
        for (int kk = 0; kk < 16; ++kk) {
            const int j = jb + (kk << 2);
            Xs[ip][j] = X[xbase + (long)(k0 + j) * HW_];
        }
        #pragma unroll
        for (int kk = 0; kk < 16; ++kk) {
            const int ol = ob + (kk << 2);
            Ws[ol][cl] = Wm[(o0 + ol) * C_ + (k0 + cl)];
        }
        __syncthreads();
        #pragma unroll
        for (int kk = 0; kk < 64; ++kk) {
            float a[4], b[4];
            #pragma unroll
            for (int ii = 0; ii < 4; ++ii) a[ii] = Xs[tr * 4 + ii][kk];
            #pragma unroll
            for (int jj = 0; jj < 4; ++jj) b[jj] = Ws[tc * 4 + jj][kk];
            #pragma unroll
            for (int ii = 0; ii < 4; ++ii)
                #pragma unroll
                for (int jj = 0; jj < 4; ++jj)
                    acc[ii][jj] = fmaf(a[ii], b[jj], acc[ii][jj]);
        }
        __syncthreads();
    }

    const int head = o0 >> 6;   // tile width 64 == head width
    #pragma unroll
    for (int ii = 0; ii < 4; ++ii) {
        const int pr = p0 + tr * 4 + ii;
        const int nn = pr / S_;
        const int ss = pr - nn * S_;
        float* dst = out + ((long)(head * N_ + nn) * S_ + ss) * D_;
        #pragma unroll
        for (int jj = 0; jj < 4; ++jj) {
            const int o = o0 + tc * 4 + jj;
            float v = acc[ii][jj] + bias[o];
            v = v > 0.f ? v : 0.f;
            dst[o & 63] = v;
        }
    }
}

// ---------------------------------------------------------------------------
// Padding masks: qm[p] / km[p] = sign(|sum_c x[p, c]|)  (1.0 or 0.0)
// ---------------------------------------------------------------------------
__global__ __launch_bounds__(64) void mask_kernel(
    const float* __restrict__ q_in, const float* __restrict__ k_in,
    float* __restrict__ qm, float* __restrict__ km)
{
    const int p = blockIdx.x;
    const int n = p / S_, s = p - n * S_;
    const int t = s / HW_, hw = s - t * HW_;
    const long base = (long)((n * T_ + t) * C_) * HW_ + hw;
    const int lane = threadIdx.x;
    float sq = 0.f, sk = 0.f;
    for (int c = lane; c < C_; c += 64) {
        sq += q_in[base + (long)c * HW_];
        sk += k_in[base + (long)c * HW_];
    }
    #pragma unroll
    for (int off = 32; off > 0; off >>= 1) {
        sq += __shfl_down(sq, off, 64);
        sk += __shfl_down(sk, off, 64);
    }
    if (lane == 0) {
        qm[p] = (sq != 0.f) ? 1.f : 0.f;
        km[p] = (sk != 0.f) ? 1.f : 0.f;
    }
}

// ---------------------------------------------------------------------------
// Flash attention, fp32. One block = one (batch b = head*N+n, 64-row Q tile).
// Writes merged-head output Om[n][s][head*64 + d].
// ---------------------------------------------------------------------------
__global__ __launch_bounds__(256) void attn_kernel(
    const float* __restrict__ Qh, const float* __restrict__ Kh,
    const float* __restrict__ Vh, const float* __restrict__ km,
    const float* __restrict__ qm, float* __restrict__ Om)
{
    __shared__ float Qs[64][65];
    __shared__ float Ks[64][65];
    __shared__ float Vs[64][65];
    __shared__ float Ps[64][65];
    __shared__ float kms[64];

    const int tid = threadIdx.x;
    const int q0 = blockIdx.x * 64;
    const int b  = blockIdx.y;            // head*N + n
    const int n  = b & (N_ - 1);
    const int head = b >> 2;

    const int tr = tid >> 4, tc = tid & 15;
    const int ip = tid & 63, jb = tid >> 6;

    {
        const int qr = q0 + ip;
        const float* src = Qh + ((long)b * S_ + (qr < S_ ? qr : 0)) * D_;
        const bool ok = qr < S_;
        #pragma unroll
        for (int kk = 0; kk < 16; ++kk) {
            const int j = jb + (kk << 2);
            Qs[ip][j] = ok ? src[j] : 0.f;
        }
    }
    float m[4], l[4], O[4][4];
    #pragma unroll
    for (int ii = 0; ii < 4; ++ii) {
        m[ii] = -INFINITY; l[ii] = 0.f;
        #pragma unroll
        for (int jj = 0; jj < 4; ++jj) O[ii][jj] = 0.f;
    }
    __syncthreads();

    const int NKT = (S_ + 63) / 64;   // 25
    for (int kt = 0; kt < NKT; ++kt) {
        const int kb = kt * 64;
        {
            const int kr = kb + ip;
            const bool ok = kr < S_;
            const long off = ((long)b * S_ + (ok ? kr : 0)) * D_;
            const float* ksrc = Kh + off;
            const float* vsrc = Vh + off;
            #pragma unroll
            for (int kk = 0; kk < 16; ++kk) {
                const int j = jb + (kk << 2);
                Ks[ip][j] = ok ? ksrc[j] : 0.f;
                Vs[ip][j] = ok ? vsrc[j] : 0.f;
            }
            if (tid < 64) kms[tid] = (kb + tid < S_) ? km[n * S_ + kb + tid] : 0.f;
        }
        __syncthreads();

        float sv[4][4] = {};
        #pragma unroll
        for (int kk = 0; kk < 64; ++kk) {
            float a[4], bb[4];
            #pragma unroll
            for (int ii = 0; ii < 4; ++ii) a[ii] = Qs[tr * 4 + ii][kk];
            #pragma unroll
            for (int jj = 0; jj < 4; ++jj) bb[jj] = Ks[tc * 4 + jj][kk];
            #pragma unroll
            for (int ii = 0; ii < 4; ++ii)
                #pragma unroll
                for (int jj = 0; jj < 4; ++jj)
                    sv[ii][jj] = fmaf(a[ii], bb[jj], sv[ii][jj]);
        }
        #pragma unroll
        for (int jj = 0; jj < 4; ++jj) {
            const int col = kb + tc * 4 + jj;
            const bool dead = (col >= S_) || (kms[tc * 4 + jj] == 0.f);
            #pragma unroll
            for (int ii = 0; ii < 4; ++ii)
                sv[ii][jj] = dead ? NEG_ : sv[ii][jj] * 0.125f;
        }
        #pragma unroll
        for (int ii = 0; ii < 4; ++ii) {
            float rmax = fmaxf(fmaxf(sv[ii][0], sv[ii][1]), fmaxf(sv[ii][2], sv[ii][3]));
            #pragma unroll
            for (int off = 8; off > 0; off >>= 1)
                rmax = fmaxf(rmax, __shfl_xor(rmax, off, 16));
            const float mn = fmaxf(m[ii], rmax);
            const float alpha = expf(m[ii] - mn);
            float rs = 0.f;
            #pragma unroll
            for (int jj = 0; jj < 4; ++jj) {
                const float pv = expf(sv[ii][jj] - mn);
                sv[ii][jj] = pv;
                rs += pv;
            }
            #pragma unroll
            for (int off = 8; off > 0; off >>= 1)
                rs += __shfl_xor(rs, off, 16);
            l[ii] = l[ii] * alpha + rs;
            m[ii] = mn;
            #pragma unroll
            for (int jj = 0; jj < 4; ++jj) O[ii][jj] *= alpha;
            #pragma unroll
            for (int jj = 0; jj < 4; ++jj) Ps[tr * 4 + ii][tc * 4 + jj] = sv[ii][jj];
        }
        __syncthreads();
        #pragma unroll
        for (int kk = 0; kk < 64; ++kk) {
            float pa[4], vb[4];
            #pragma unroll
            for (int ii = 0; ii < 4; ++ii) pa[ii] = Ps[tr * 4 + ii][kk];
            #pragma unroll
            for (int jj = 0; jj < 4; ++jj) vb[jj] = Vs[kk][tc * 4 + jj];
            #pragma unroll
            for (int ii = 0; ii < 4; ++ii)
                #pragma unroll
                for (int jj = 0; jj < 4; ++jj)
                    O[ii][jj] = fmaf(pa[ii], vb[jj], O[ii][jj]);
        }
        __syncthreads();
    }

    #pragma unroll
    for (int ii = 0; ii < 4; ++ii) {
        const int qr = q0 + tr * 4 + ii;
        if (qr < S_) {
            const float qmv = qm[n * S_ + qr];
            const float inv = qmv / l[ii];
            float* dst = Om + ((long)n * S_ + qr) * C_ + head * D_ + tc * 4;
            #pragma unroll
            for (int jj = 0; jj < 4; ++jj) dst[jj] = O[ii][jj] * inv;
        }
    }
}

// ---------------------------------------------------------------------------
// Residual + unbiased-std LayerNorm + reshape back to (N,T,C,H,W)
// ---------------------------------------------------------------------------
__global__ __launch_bounds__(128) void ln_kernel(
    const float* __restrict__ Om, const float* __restrict__ q_in,
    const float* __restrict__ gamma, const float* __restrict__ beta,
    float* __restrict__ out)
{
    __shared__ float red[4];
    const int p = blockIdx.x;
    const int n = p / S_, s = p - n * S_;
    const int t = s / HW_, hw = s - t * HW_;
    const long qbase = (long)((n * T_ + t) * C_) * HW_ + hw;
    const int tid = threadIdx.x;

    float x[4];
    float sum = 0.f, ssq = 0.f;
    #pragma unroll
    for (int k = 0; k < 4; ++k) {
        const int c = tid + k * 128;
        const float v = Om[(long)p * C_ + c] + q_in[qbase + (long)c * HW_];
        x[k] = v;
        sum += v; ssq += v * v;
    }
    #pragma unroll
    for (int off = 32; off > 0; off >>= 1) {
        sum += __shfl_down(sum, off, 64);
        ssq += __shfl_down(ssq, off, 64);
    }
    const int wave = tid >> 6, lane = tid & 63;
    if (lane == 0) { red[wave * 2] = sum; red[wave * 2 + 1] = ssq; }
    __syncthreads();
    sum = red[0] + red[2];
    ssq = red[1] + red[3];
    const float mean = sum * (1.f / 512.f);
    float var = (ssq - sum * mean) * (1.f / 511.f);
    var = var > 0.f ? var : 0.f;
    const float inv = 1.f / (sqrtf(var) + EPS_);
    #pragma unroll
    for (int k = 0; k < 4; ++k) {
        const int c = tid + k * 128;
        out[qbase + (long)c * HW_] = gamma[c] * (x[k] - mean) * inv + beta[c];
    }
}

extern "C" void kernel_launch(void* const* d_in, const int* in_sizes, int n_in,
                              void* d_out, int out_size, void* d_ws, size_t ws_size,
                              hipStream_t stream) {
    const float* q_in  = (const float*)d_in[0];
    const float* k_in  = (const float*)d_in[1];
    const float* v_in  = (const float*)d_in[2];
    const float* Wq    = (const float*)d_in[3];
    const float* bq    = (const float*)d_in[4];
    const float* Wk    = (const float*)d_in[5];
    const float* bk    = (const float*)d_in[6];
    const float* Wv    = (const float*)d_in[7];
    const float* bv    = (const float*)d_in[8];
    const float* gamma = (const float*)d_in[9];
    const float* beta  = (const float*)d_in[10];
    float* out = (float*)d_out;

    float* ws = (float*)d_ws;
    const size_t SZ = (size_t)HEADS_ * N_ * S_ * D_;  // 3,211,264 floats
    float* Qh = ws;
    float* Kh = Qh + SZ;
    float* Vh = Kh + SZ;
    float* Om = Vh + SZ;
    float* km = Om + SZ;
    float* qm = km + P_TOT;

    proj_kernel<<<dim3(98, 8), 256, 0, stream>>>(q_in, Wq, bq, Qh);
    proj_kernel<<<dim3(98, 8), 256, 0, stream>>>(k_in, Wk, bk, Kh);
    proj_kernel<<<dim3(98, 8), 256, 0, stream>>>(v_in, Wv, bv, Vh);
    mask_kernel<<<P_TOT, 64, 0, stream>>>(q_in, k_in, qm, km);
    attn_kernel<<<dim3(25, 32), 256, 0, stream>>>(Qh, Kh, Vh, km, qm, Om);
    ln_kernel<<<P_TOT, 128, 0, stream>>>(Om, q_in, gamma, beta, out);
}

// Round 2
// 478.876 us; speedup vs baseline: 4.8945x; 4.8945x over previous
//
#include <hip/hip_runtime.h>
#include <math.h>

#define N_ 4
#define T_ 8
#define C_ 512
#define H_ 14
#define W_ 14
#define HEADS_ 8
#define D_ 64
#define HW_ 196
#define S_ 1568
#define P_TOT 6272
#define NEG_ (-4294967295.0f)
#define EPS_ 1e-8f

typedef __attribute__((ext_vector_type(8))) short short8v;
typedef __attribute__((ext_vector_type(4))) float float4v;
typedef unsigned short ushort_t;

__device__ __forceinline__ ushort_t f2bf(float f) {
    union { float f; unsigned u; } a; a.f = f;
    unsigned r = (a.u + 0x7FFFu + ((a.u >> 16) & 1u)) >> 16;
    return (ushort_t)r;
}

__device__ __forceinline__ float4v mfma16(short8v a, short8v b, float4v c) {
    return __builtin_amdgcn_mfma_f32_16x16x32_bf16(a, b, c, 0, 0, 0);
}

// ---------------------------------------------------------------------------
// Projection GEMM (fp32 compute, bf16 output): Y[p,o] = relu(sum_c X[p,c]W[o,c]+b[o])
// TRANS=0: out[(head*N+n)*S + s][d]   (Q, K)
// TRANS=1: out[(head*N+n)*D + d][s]   (V, pre-transposed for attention)
// ---------------------------------------------------------------------------
template <int TRANS>
__global__ __launch_bounds__(256) void proj_kernel(
    const float* __restrict__ X, const float* __restrict__ Wm,
    const float* __restrict__ bias, ushort_t* __restrict__ out)
{
    __shared__ float Xs[64][65];
    __shared__ float Ws[64][65];
    const int tid = threadIdx.x;
    const int p0 = blockIdx.x * 64;
    const int o0 = blockIdx.y * 64;

    const int tr = tid >> 4, tc = tid & 15;
    const int ip = tid & 63;
    const int jb = tid >> 6;

    const int p = p0 + ip;
    const int n = p / S_;
    const int s = p - n * S_;
    const int t = s / HW_;
    const int hw = s - t * HW_;
    const long xbase = (long)((n * T_ + t) * C_) * HW_ + hw;

    const int cl = tid & 63;
    const int ob = tid >> 6;

    float acc[4][4] = {};
    for (int k0 = 0; k0 < C_; k0 += 64) {
        #pragma unroll
        for (int kk = 0; kk < 16; ++kk) {
            const int j = jb + (kk << 2);
            Xs[ip][j] = X[xbase + (long)(k0 + j) * HW_];
        }
        #pragma unroll
        for (int kk = 0; kk < 16; ++kk) {
            const int ol = ob + (kk << 2);
            Ws[ol][cl] = Wm[(o0 + ol) * C_ + (k0 + cl)];
        }
        __syncthreads();
        #pragma unroll
        for (int kk = 0; kk < 64; ++kk) {
            float a[4], b[4];
            #pragma unroll
            for (int ii = 0; ii < 4; ++ii) a[ii] = Xs[tr * 4 + ii][kk];
            #pragma unroll
            for (int jj = 0; jj < 4; ++jj) b[jj] = Ws[tc * 4 + jj][kk];
            #pragma unroll
            for (int ii = 0; ii < 4; ++ii)
                #pragma unroll
                for (int jj = 0; jj < 4; ++jj)
                    acc[ii][jj] = fmaf(a[ii], b[jj], acc[ii][jj]);
        }
        __syncthreads();
    }

    const int head = o0 >> 6;
    #pragma unroll
    for (int ii = 0; ii < 4; ++ii) {
        const int pr = p0 + tr * 4 + ii;
        const int nn = pr / S_;
        const int ss = pr - nn * S_;
        #pragma unroll
        for (int jj = 0; jj < 4; ++jj) {
            const int o = o0 + tc * 4 + jj;
            float v = acc[ii][jj] + bias[o];
            v = v > 0.f ? v : 0.f;
            if (TRANS)
                out[((long)(head * N_ + nn) * D_ + (o & 63)) * S_ + ss] = f2bf(v);
            else
                out[((long)(head * N_ + nn) * S_ + ss) * D_ + (o & 63)] = f2bf(v);
        }
    }
}

// ---------------------------------------------------------------------------
// Padding masks: qm[p] / km[p] = sign(|sum_c x[p, c]|)
// ---------------------------------------------------------------------------
__global__ __launch_bounds__(64) void mask_kernel(
    const float* __restrict__ q_in, const float* __restrict__ k_in,
    float* __restrict__ qm, float* __restrict__ km)
{
    const int p = blockIdx.x;
    const int n = p / S_, s = p - n * S_;
    const int t = s / HW_, hw = s - t * HW_;
    const long base = (long)((n * T_ + t) * C_) * HW_ + hw;
    const int lane = threadIdx.x;
    float sq = 0.f, sk = 0.f;
    for (int c = lane; c < C_; c += 64) {
        sq += q_in[base + (long)c * HW_];
        sk += k_in[base + (long)c * HW_];
    }
    #pragma unroll
    for (int off = 32; off > 0; off >>= 1) {
        sq += __shfl_down(sq, off, 64);
        sk += __shfl_down(sk, off, 64);
    }
    if (lane == 0) {
        qm[p] = (sq != 0.f) ? 1.f : 0.f;
        km[p] = (sk != 0.f) ? 1.f : 0.f;
    }
}

// ---------------------------------------------------------------------------
// MFMA flash attention (swapped-operand form).
// Block = 256 threads (4 waves), one batch b = head*N+n, 64 q rows.
// Wave w owns q cols [w*16, w*16+16). S^T = K·Q^T so softmax is lane-local per q
// (reduce over 4 lane-groups via shfl_xor 16/32); P^T regs feed PV directly:
// out^T = V^T · P^T. K/V^T tiles staged in LDS with ^((row&7)<<4) swizzle.
// ---------------------------------------------------------------------------
__global__ __launch_bounds__(256) void attn_kernel(
    const ushort_t* __restrict__ Qh, const ushort_t* __restrict__ Kh,
    const ushort_t* __restrict__ Vt, const float* __restrict__ km,
    const float* __restrict__ qm, float* __restrict__ Om)
{
    __shared__ char lds[2 * 8192 + 256];
    char* Klds = lds;
    char* Vlds = lds + 8192;
    float* kms = (float*)(lds + 16384);

    const int tid = threadIdx.x;
    const int lane = tid & 63;
    const int w = tid >> 6;
    const int lg = lane >> 4;
    const int lo = lane & 15;

    const int q0 = blockIdx.x * 64;
    const int b = blockIdx.y;
    const int n = b & (N_ - 1);
    const int head = b >> 2;

    // Q fragments hoisted to registers: n=q (lo), kk=d
    const int qrow = q0 + w * 16 + lo;
    const int qcl = qrow < S_ ? qrow : S_ - 1;
    const ushort_t* qp = Qh + ((long)b * S_ + qcl) * D_ + lg * 4;
    short8v qf[2];
    #pragma unroll
    for (int ks = 0; ks < 2; ++ks) {
        ((uint2*)&qf[ks])[0] = *(const uint2*)(qp + ks * 32);
        ((uint2*)&qf[ks])[1] = *(const uint2*)(qp + ks * 32 + 16);
    }

    float4v acc[4];
    #pragma unroll
    for (int dt = 0; dt < 4; ++dt) acc[dt] = (float4v){0.f, 0.f, 0.f, 0.f};
    float m_run = -INFINITY, l_run = 0.f;

    const int sr = tid >> 2;          // staging row 0..63
    const int sseg = tid & 3;         // 16-element segment
    const int sw = (sr & 7) << 4;
    const int kbase = sr * 128 + sseg * 32;

    for (int kb = 0; kb < S_; kb += 64) {
        // ---- stage K tile [64 k][64 d] and V^T tile [64 d][64 k], swizzled ----
        {
            int krow = kb + sr; if (krow >= S_) krow = S_ - 1;
            const uint4* kg = (const uint4*)(Kh + ((long)b * S_ + krow) * D_ + sseg * 16);
            uint4 kv0 = kg[0], kv1 = kg[1];
            int c0 = kb + sseg * 16; if (c0 > S_ - 16) c0 = S_ - 16;
            const uint4* vg = (const uint4*)(Vt + ((long)b * D_ + sr) * S_ + c0);
            uint4 vv0 = vg[0], vv1 = vg[1];
            *(uint4*)(Klds + (kbase ^ sw)) = kv0;
            *(uint4*)(Klds + ((kbase + 16) ^ sw)) = kv1;
            *(uint4*)(Vlds + (kbase ^ sw)) = vv0;
            *(uint4*)(Vlds + ((kbase + 16) ^ sw)) = vv1;
            if (tid < 64) kms[tid] = (kb + tid < S_) ? km[n * S_ + kb + tid] : 0.f;
        }
        __syncthreads();

        // ---- QK^T: s[kt] = S^T tile rows kt*16.., cols = wave's 16 q ----
        float4v s[4];
        #pragma unroll
        for (int kt = 0; kt < 4; ++kt) {
            s[kt] = (float4v){0.f, 0.f, 0.f, 0.f};
            #pragma unroll
            for (int ks = 0; ks < 2; ++ks) {
                const int row = kt * 16 + lo;
                const int base = row * 128 + ks * 64 + lg * 8;
                const int swr = (row & 7) << 4;
                short8v kf;
                ((uint2*)&kf)[0] = *(const uint2*)(Klds + (base ^ swr));
                ((uint2*)&kf)[1] = *(const uint2*)(Klds + ((base + 32) ^ swr));
                s[kt] = mfma16(kf, qf[ks], s[kt]);
            }
        }

        // ---- online softmax (per lane: 16 k values of one q column) ----
        float p[4][4];
        float mx = -INFINITY;
        #pragma unroll
        for (int kt = 0; kt < 4; ++kt) {
            const float4v km4 = *(const float4v*)&kms[kt * 16 + lg * 4];
            #pragma unroll
            for (int r = 0; r < 4; ++r) {
                const int krow = kb + kt * 16 + lg * 4 + r;
                float sv = (km4[r] != 0.f) ? s[kt][r] * 0.125f : NEG_;
                if (krow >= S_) sv = -INFINITY;
                p[kt][r] = sv;
                mx = fmaxf(mx, sv);
            }
        }
        mx = fmaxf(mx, __shfl_xor(mx, 16, 64));
        mx = fmaxf(mx, __shfl_xor(mx, 32, 64));
        const float mn = fmaxf(m_run, mx);
        const float alpha = __expf(m_run - mn);
        m_run = mn;
        float rs = 0.f;
        #pragma unroll
        for (int kt = 0; kt < 4; ++kt)
            #pragma unroll
            for (int r = 0; r < 4; ++r) {
                const float pv = __expf(p[kt][r] - mn);
                p[kt][r] = pv;
                rs += pv;
            }
        rs += __shfl_xor(rs, 16, 64);
        rs += __shfl_xor(rs, 32, 64);
        l_run = l_run * alpha + rs;
        #pragma unroll
        for (int dt = 0; dt < 4; ++dt)
            #pragma unroll
            for (int r = 0; r < 4; ++r) acc[dt][r] *= alpha;

        // ---- P^T registers ARE the PV B-operand after bf16 convert ----
        short8v pf[2];
        #pragma unroll
        for (int ks = 0; ks < 2; ++ks)
            #pragma unroll
            for (int e = 0; e < 8; ++e)
                ((ushort_t*)&pf[ks])[e] = f2bf(p[ks * 2 + (e >> 2)][e & 3]);

        // ---- PV: out^T[d][q] += V^T · P^T ----
        #pragma unroll
        for (int dt = 0; dt < 4; ++dt) {
            #pragma unroll
            for (int ks = 0; ks < 2; ++ks) {
                const int row = dt * 16 + lo;
                const int base = row * 128 + ks * 64 + lg * 8;
                const int swr = (row & 7) << 4;
                short8v vf;
                ((uint2*)&vf)[0] = *(const uint2*)(Vlds + (base ^ swr));
                ((uint2*)&vf)[1] = *(const uint2*)(Vlds + ((base + 32) ^ swr));
                acc[dt] = mfma16(vf, pf[ks], acc[dt]);
            }
        }
        __syncthreads();
    }

    // ---- epilogue: acc[dt][r] = out^T[dt*16+lg*4+r][q=lo] ----
    if (qrow < S_) {
        const float inv = qm[n * S_ + qrow] / l_run;
        float* dst = Om + ((long)n * S_ + qrow) * C_ + head * D_;
        #pragma unroll
        for (int dt = 0; dt < 4; ++dt) {
            float4v o;
            #pragma unroll
            for (int r = 0; r < 4; ++r) o[r] = acc[dt][r] * inv;
            *(float4v*)(dst + dt * 16 + lg * 4) = o;
        }
    }
}

// ---------------------------------------------------------------------------
// Residual + unbiased-std LayerNorm + reshape back to (N,T,C,H,W)
// ---------------------------------------------------------------------------
__global__ __launch_bounds__(128) void ln_kernel(
    const float* __restrict__ Om, const float* __restrict__ q_in,
    const float* __restrict__ gamma, const float* __restrict__ beta,
    float* __restrict__ out)
{
    __shared__ float red[4];
    const int p = blockIdx.x;
    const int n = p / S_, s = p - n * S_;
    const int t = s / HW_, hw = s - t * HW_;
    const long qbase = (long)((n * T_ + t) * C_) * HW_ + hw;
    const int tid = threadIdx.x;

    float x[4];
    float sum = 0.f, ssq = 0.f;
    #pragma unroll
    for (int k = 0; k < 4; ++k) {
        const int c = tid + k * 128;
        const float v = Om[(long)p * C_ + c] + q_in[qbase + (long)c * HW_];
        x[k] = v;
        sum += v; ssq += v * v;
    }
    #pragma unroll
    for (int off = 32; off > 0; off >>= 1) {
        sum += __shfl_down(sum, off, 64);
        ssq += __shfl_down(ssq, off, 64);
    }
    const int wave = tid >> 6, lane = tid & 63;
    if (lane == 0) { red[wave * 2] = sum; red[wave * 2 + 1] = ssq; }
    __syncthreads();
    sum = red[0] + red[2];
    ssq = red[1] + red[3];
    const float mean = sum * (1.f / 512.f);
    float var = (ssq - sum * mean) * (1.f / 511.f);
    var = var > 0.f ? var : 0.f;
    const float inv = 1.f / (sqrtf(var) + EPS_);
    #pragma unroll
    for (int k = 0; k < 4; ++k) {
        const int c = tid + k * 128;
        out[qbase + (long)c * HW_] = gamma[c] * (x[k] - mean) * inv + beta[c];
    }
}

extern "C" void kernel_launch(void* const* d_in, const int* in_sizes, int n_in,
                              void* d_out, int out_size, void* d_ws, size_t ws_size,
                              hipStream_t stream) {
    const float* q_in  = (const float*)d_in[0];
    const float* k_in  = (const float*)d_in[1];
    const float* v_in  = (const float*)d_in[2];
    const float* Wq    = (const float*)d_in[3];
    const float* bq    = (const float*)d_in[4];
    const float* Wk    = (const float*)d_in[5];
    const float* bk    = (const float*)d_in[6];
    const float* Wv    = (const float*)d_in[7];
    const float* bv    = (const float*)d_in[8];
    const float* gamma = (const float*)d_in[9];
    const float* beta  = (const float*)d_in[10];
    float* out = (float*)d_out;

    const size_t QSZ = (size_t)HEADS_ * N_ * S_ * D_;  // 3,211,264 elements
    ushort_t* Qh = (ushort_t*)d_ws;
    ushort_t* Kh = Qh + QSZ;
    ushort_t* Vt = Kh + QSZ;
    float* Om = (float*)(Vt + QSZ);
    float* km = Om + QSZ;
    float* qm = km + P_TOT;

    proj_kernel<0><<<dim3(98, 8), 256, 0, stream>>>(q_in, Wq, bq, Qh);
    proj_kernel<0><<<dim3(98, 8), 256, 0, stream>>>(k_in, Wk, bk, Kh);
    proj_kernel<1><<<dim3(98, 8), 256, 0, stream>>>(v_in, Wv, bv, Vt);
    mask_kernel<<<P_TOT, 64, 0, stream>>>(q_in, k_in, qm, km);
    attn_kernel<<<dim3(25, 32), 256, 0, stream>>>(Qh, Kh, Vt, km, qm, Om);
    ln_kernel<<<P_TOT, 128, 0, stream>>>(Om, q_in, gamma, beta, out);
}

// Round 3
// 237.814 us; speedup vs baseline: 9.8558x; 2.0137x over previous
//
#include <hip/hip_runtime.h>
#include <math.h>

#define N_ 4
#define T_ 8
#define C_ 512
#define H_ 14
#define W_ 14
#define HEADS_ 8
#define D_ 64
#define HW_ 196
#define S_ 1568
#define P_TOT 6272
#define NEG_ (-4294967295.0f)
#define EPS_ 1e-8f

typedef __attribute__((ext_vector_type(8))) short short8v;
typedef __attribute__((ext_vector_type(4))) float float4v;
typedef __attribute__((ext_vector_type(4))) unsigned short ushort4v;
typedef unsigned short ushort_t;

__device__ __forceinline__ ushort_t f2bf(float f) {
    union { float f; unsigned u; } a; a.f = f;
    unsigned r = (a.u + 0x7FFFu + ((a.u >> 16) & 1u)) >> 16;
    return (ushort_t)r;
}
__device__ __forceinline__ float bf2f(ushort_t u) {
    union { unsigned u; float f; } t; t.u = ((unsigned)u) << 16; return t.f;
}

__device__ __forceinline__ float4v mfma16(short8v a, short8v b, float4v c) {
    return __builtin_amdgcn_mfma_f32_16x16x32_bf16(a, b, c, 0, 0, 0);
}

// ---------------------------------------------------------------------------
// Transpose pre-pass: (N,T,C,H,W) fp32 -> [p][c] bf16  (p = nt*196 + hw)
// Block = (nt, ctile of 64 c). LDS [64][197] staging, coalesced both sides.
// ---------------------------------------------------------------------------
__global__ __launch_bounds__(256) void transpose_kernel(
    const float* __restrict__ q_in, const float* __restrict__ k_in,
    const float* __restrict__ v_in, ushort_t* __restrict__ qbf,
    ushort_t* __restrict__ kbf, ushort_t* __restrict__ vbf)
{
    __shared__ float Xs[64][197];
    const int z = blockIdx.z;
    const float* src = (z == 0) ? q_in : (z == 1) ? k_in : v_in;
    ushort_t* dst = (z == 0) ? qbf : (z == 1) ? kbf : vbf;

    const int nt = blockIdx.x;       // n*8 + t
    const int ct = blockIdx.y;       // 64-channel tile
    const int tid = threadIdx.x;

    const long gbase = ((long)nt * C_ + ct * 64) * HW_;
    #pragma unroll 7
    for (int i = 0; i < 49; ++i) {
        const int e = i * 256 + tid;          // 0..12543
        const int row = e / HW_;
        const int hw = e - row * HW_;
        Xs[row][hw] = src[gbase + (long)row * HW_ + hw];
    }
    __syncthreads();
    #pragma unroll 7
    for (int i = 0; i < 49; ++i) {
        const int e = i * 256 + tid;
        const int c = e & 63;
        const int hw = e >> 6;
        const long p = (long)nt * HW_ + hw;
        dst[p * C_ + ct * 64 + c] = f2bf(Xs[c][hw]);
    }
}

// ---------------------------------------------------------------------------
// Weight convert fp32 -> bf16 (3 weights)
// ---------------------------------------------------------------------------
__global__ __launch_bounds__(256) void wconv_kernel(
    const float* __restrict__ Wq, const float* __restrict__ Wk,
    const float* __restrict__ Wv, ushort_t* __restrict__ Wbf)
{
    const int z = blockIdx.y;
    const float* src = (z == 0) ? Wq : (z == 1) ? Wk : Wv;
    const int idx = blockIdx.x * 256 + threadIdx.x;   // 0..262143
    Wbf[(long)z * 262144 + idx] = f2bf(src[idx]);
}

// ---------------------------------------------------------------------------
// Padding masks from transposed bf16 copies (coalesced). 4 waves = 4 positions.
// ---------------------------------------------------------------------------
__global__ __launch_bounds__(256) void mask_kernel(
    const ushort_t* __restrict__ qbf, const ushort_t* __restrict__ kbf,
    float* __restrict__ qm, float* __restrict__ km)
{
    const int tid = threadIdx.x;
    const int w = tid >> 6, lane = tid & 63;
    const int p = blockIdx.x * 4 + w;
    const short8v qv = *(const short8v*)(qbf + (long)p * C_ + lane * 8);
    const short8v kv = *(const short8v*)(kbf + (long)p * C_ + lane * 8);
    float sq = 0.f, sk = 0.f;
    #pragma unroll
    for (int j = 0; j < 8; ++j) {
        sq += bf2f(((const ushort_t*)&qv)[j]);
        sk += bf2f(((const ushort_t*)&kv)[j]);
    }
    #pragma unroll
    for (int off = 32; off > 0; off >>= 1) {
        sq += __shfl_xor(sq, off, 64);
        sk += __shfl_xor(sk, off, 64);
    }
    if (lane == 0) {
        qm[p] = (sq != 0.f) ? 1.f : 0.f;
        km[p] = (sk != 0.f) ? 1.f : 0.f;
    }
}

// ---------------------------------------------------------------------------
// MFMA projection: Y[p,o] = relu(sum_c Xbf[p,c]*Wbf[o,c] + bias[o])
// BM=128 p x BN=64 o (one head). 4 waves 2x2 (wave: 64p x 32o).
// TRANS=0: out[b][s][d] (Q,K).  TRANS=1: out[b][d][s] (V^T).
// LDS: X tile [128][128B], W tile [64][128B], 16B-slot XOR swizzle (^(row&7)).
// ---------------------------------------------------------------------------
template <int TRANS>
__global__ __launch_bounds__(256) void proj_mfma(
    const ushort_t* __restrict__ Xbf, const ushort_t* __restrict__ Wbf,
    const float* __restrict__ bias, ushort_t* __restrict__ outp)
{
    __shared__ char lds[24576];
    char* Xl = lds;
    char* Wl = lds + 16384;
    const int tid = threadIdx.x;
    const int w = tid >> 6, lane = tid & 63, lg = lane >> 4, lo = lane & 15;
    const int wr = w >> 1, wc = w & 1;
    const int p0 = blockIdx.x * 128;
    const int head = blockIdx.y;
    const int o0 = head * 64;

    float4v acc[2][4];
    #pragma unroll
    for (int a = 0; a < 2; ++a)
        #pragma unroll
        for (int b = 0; b < 4; ++b) acc[a][b] = (float4v){0.f, 0.f, 0.f, 0.f};

    for (int k0 = 0; k0 < C_; k0 += 64) {
        uint4 xs[4], wsv[2];
        #pragma unroll
        for (int i = 0; i < 4; ++i) {
            const int sl = tid + i * 256;
            const int row = sl >> 3, sir = sl & 7;
            const int c16 = sir ^ (row & 7);
            xs[i] = *(const uint4*)(Xbf + (long)(p0 + row) * C_ + k0 + c16 * 8);
        }
        #pragma unroll
        for (int i = 0; i < 2; ++i) {
            const int sl = tid + i * 256;
            const int row = sl >> 3, sir = sl & 7;
            const int c16 = sir ^ (row & 7);
            wsv[i] = *(const uint4*)(Wbf + (long)(o0 + row) * C_ + k0 + c16 * 8);
        }
        __syncthreads();
        #pragma unroll
        for (int i = 0; i < 4; ++i) *(uint4*)(Xl + (tid + i * 256) * 16) = xs[i];
        #pragma unroll
        for (int i = 0; i < 2; ++i) *(uint4*)(Wl + (tid + i * 256) * 16) = wsv[i];
        __syncthreads();

        short8v wf[2][2], xf[4][2];
        #pragma unroll
        for (int a = 0; a < 2; ++a) {
            const int row = wc * 32 + a * 16 + lo;
            const int swr = (row & 7) << 4;
            #pragma unroll
            for (int ks = 0; ks < 2; ++ks) {
                const int base = row * 128 + ks * 64 + lg * 8;
                ((uint2*)&wf[a][ks])[0] = *(const uint2*)(Wl + (base ^ swr));
                ((uint2*)&wf[a][ks])[1] = *(const uint2*)(Wl + ((base + 32) ^ swr));
            }
        }
        #pragma unroll
        for (int b = 0; b < 4; ++b) {
            const int row = wr * 64 + b * 16 + lo;
            const int swr = (row & 7) << 4;
            #pragma unroll
            for (int ks = 0; ks < 2; ++ks) {
                const int base = row * 128 + ks * 64 + lg * 8;
                ((uint2*)&xf[b][ks])[0] = *(const uint2*)(Xl + (base ^ swr));
                ((uint2*)&xf[b][ks])[1] = *(const uint2*)(Xl + ((base + 32) ^ swr));
            }
        }
        #pragma unroll
        for (int ks = 0; ks < 2; ++ks)
            #pragma unroll
            for (int a = 0; a < 2; ++a)
                #pragma unroll
                for (int b = 0; b < 4; ++b)
                    acc[a][b] = TRANS ? mfma16(xf[b][ks], wf[a][ks], acc[a][b])
                                      : mfma16(wf[a][ks], xf[b][ks], acc[a][b]);
        __syncthreads();
    }

    if (TRANS == 0) {
        // D: m = o (row = lg*4+reg within frag a), n = p (col = lo within frag b)
        #pragma unroll
        for (int b = 0; b < 4; ++b) {
            const int p = p0 + wr * 64 + b * 16 + lo;
            const int nb = p / S_;
            const int s = p - nb * S_;
            #pragma unroll
            for (int a = 0; a < 2; ++a) {
                const int d0 = wc * 32 + a * 16 + lg * 4;
                const float4v bs = *(const float4v*)(bias + o0 + d0);
                ushort4v pk;
                #pragma unroll
                for (int e = 0; e < 4; ++e) {
                    float v = acc[a][b][e] + bs[e];
                    v = v > 0.f ? v : 0.f;
                    pk[e] = f2bf(v);
                }
                *(ushort4v*)(outp + ((long)(head * N_ + nb) * S_ + s) * D_ + d0) = pk;
            }
        }
    } else {
        // D: m = p (row), n = o (col = lo)
        #pragma unroll
        for (int a = 0; a < 2; ++a) {
            const int d = wc * 32 + a * 16 + lo;
            const float bsc = bias[o0 + d];
            #pragma unroll
            for (int b = 0; b < 4; ++b) {
                const int pb = p0 + wr * 64 + b * 16 + lg * 4;
                const int nb = pb / S_;
                const int s0 = pb - nb * S_;
                ushort4v pk;
                #pragma unroll
                for (int e = 0; e < 4; ++e) {
                    float v = acc[a][b][e] + bsc;
                    v = v > 0.f ? v : 0.f;
                    pk[e] = f2bf(v);
                }
                *(ushort4v*)(outp + ((long)(head * N_ + nb) * D_ + d) * S_ + s0) = pk;
            }
        }
    }
}

// ---------------------------------------------------------------------------
// MFMA flash attention (unchanged from round 2 — verified).
// ---------------------------------------------------------------------------
__global__ __launch_bounds__(256) void attn_kernel(
    const ushort_t* __restrict__ Qh, const ushort_t* __restrict__ Kh,
    const ushort_t* __restrict__ Vt, const float* __restrict__ km,
    const float* __restrict__ qm, float* __restrict__ Om)
{
    __shared__ char lds[2 * 8192 + 256];
    char* Klds = lds;
    char* Vlds = lds + 8192;
    float* kms = (float*)(lds + 16384);

    const int tid = threadIdx.x;
    const int lane = tid & 63;
    const int w = tid >> 6;
    const int lg = lane >> 4;
    const int lo = lane & 15;

    const int q0 = blockIdx.x * 64;
    const int b = blockIdx.y;
    const int n = b & (N_ - 1);
    const int head = b >> 2;

    const int qrow = q0 + w * 16 + lo;
    const int qcl = qrow < S_ ? qrow : S_ - 1;
    const ushort_t* qp = Qh + ((long)b * S_ + qcl) * D_ + lg * 4;
    short8v qf[2];
    #pragma unroll
    for (int ks = 0; ks < 2; ++ks) {
        ((uint2*)&qf[ks])[0] = *(const uint2*)(qp + ks * 32);
        ((uint2*)&qf[ks])[1] = *(const uint2*)(qp + ks * 32 + 16);
    }

    float4v acc[4];
    #pragma unroll
    for (int dt = 0; dt < 4; ++dt) acc[dt] = (float4v){0.f, 0.f, 0.f, 0.f};
    float m_run = -INFINITY, l_run = 0.f;

    const int sr = tid >> 2;
    const int sseg = tid & 3;
    const int sw = (sr & 7) << 4;
    const int kbase = sr * 128 + sseg * 32;

    for (int kb = 0; kb < S_; kb += 64) {
        {
            int krow = kb + sr; if (krow >= S_) krow = S_ - 1;
            const uint4* kg = (const uint4*)(Kh + ((long)b * S_ + krow) * D_ + sseg * 16);
            uint4 kv0 = kg[0], kv1 = kg[1];
            int c0 = kb + sseg * 16; if (c0 > S_ - 16) c0 = S_ - 16;
            const uint4* vg = (const uint4*)(Vt + ((long)b * D_ + sr) * S_ + c0);
            uint4 vv0 = vg[0], vv1 = vg[1];
            *(uint4*)(Klds + (kbase ^ sw)) = kv0;
            *(uint4*)(Klds + ((kbase + 16) ^ sw)) = kv1;
            *(uint4*)(Vlds + (kbase ^ sw)) = vv0;
            *(uint4*)(Vlds + ((kbase + 16) ^ sw)) = vv1;
            if (tid < 64) kms[tid] = (kb + tid < S_) ? km[n * S_ + kb + tid] : 0.f;
        }
        __syncthreads();

        float4v s[4];
        #pragma unroll
        for (int kt = 0; kt < 4; ++kt) {
            s[kt] = (float4v){0.f, 0.f, 0.f, 0.f};
            #pragma unroll
            for (int ks = 0; ks < 2; ++ks) {
                const int row = kt * 16 + lo;
                const int base = row * 128 + ks * 64 + lg * 8;
                const int swr = (row & 7) << 4;
                short8v kf;
                ((uint2*)&kf)[0] = *(const uint2*)(Klds + (base ^ swr));
                ((uint2*)&kf)[1] = *(const uint2*)(Klds + ((base + 32) ^ swr));
                s[kt] = mfma16(kf, qf[ks], s[kt]);
            }
        }

        float p[4][4];
        float mx = -INFINITY;
        #pragma unroll
        for (int kt = 0; kt < 4; ++kt) {
            const float4v km4 = *(const float4v*)&kms[kt * 16 + lg * 4];
            #pragma unroll
            for (int r = 0; r < 4; ++r) {
                const int krow = kb + kt * 16 + lg * 4 + r;
                float sv = (km4[r] != 0.f) ? s[kt][r] * 0.125f : NEG_;
                if (krow >= S_) sv = -INFINITY;
                p[kt][r] = sv;
                mx = fmaxf(mx, sv);
            }
        }
        mx = fmaxf(mx, __shfl_xor(mx, 16, 64));
        mx = fmaxf(mx, __shfl_xor(mx, 32, 64));
        const float mn = fmaxf(m_run, mx);
        const float alpha = __expf(m_run - mn);
        m_run = mn;
        float rs = 0.f;
        #pragma unroll
        for (int kt = 0; kt < 4; ++kt)
            #pragma unroll
            for (int r = 0; r < 4; ++r) {
                const float pv = __expf(p[kt][r] - mn);
                p[kt][r] = pv;
                rs += pv;
            }
        rs += __shfl_xor(rs, 16, 64);
        rs += __shfl_xor(rs, 32, 64);
        l_run = l_run * alpha + rs;
        #pragma unroll
        for (int dt = 0; dt < 4; ++dt)
            #pragma unroll
            for (int r = 0; r < 4; ++r) acc[dt][r] *= alpha;

        short8v pf[2];
        #pragma unroll
        for (int ks = 0; ks < 2; ++ks)
            #pragma unroll
            for (int e = 0; e < 8; ++e)
                ((ushort_t*)&pf[ks])[e] = f2bf(p[ks * 2 + (e >> 2)][e & 3]);

        #pragma unroll
        for (int dt = 0; dt < 4; ++dt) {
            #pragma unroll
            for (int ks = 0; ks < 2; ++ks) {
                const int row = dt * 16 + lo;
                const int base = row * 128 + ks * 64 + lg * 8;
                const int swr = (row & 7) << 4;
                short8v vf;
                ((uint2*)&vf)[0] = *(const uint2*)(Vlds + (base ^ swr));
                ((uint2*)&vf)[1] = *(const uint2*)(Vlds + ((base + 32) ^ swr));
                acc[dt] = mfma16(vf, pf[ks], acc[dt]);
            }
        }
        __syncthreads();
    }

    if (qrow < S_) {
        const float inv = qm[n * S_ + qrow] / l_run;
        float* dst = Om + ((long)n * S_ + qrow) * C_ + head * D_;
        #pragma unroll
        for (int dt = 0; dt < 4; ++dt) {
            float4v o;
            #pragma unroll
            for (int r = 0; r < 4; ++r) o[r] = acc[dt][r] * inv;
            *(float4v*)(dst + dt * 16 + lg * 4) = o;
        }
    }
}

// ---------------------------------------------------------------------------
// LN pass 1: per-position mean and 1/(std+eps). 4 waves = 4 positions.
// ---------------------------------------------------------------------------
__global__ __launch_bounds__(256) void ln_stats_kernel(
    const float* __restrict__ Om, const ushort_t* __restrict__ qbf,
    float* __restrict__ stats)
{
    const int tid = threadIdx.x;
    const int w = tid >> 6, lane = tid & 63;
    const long p = blockIdx.x * 4 + w;
    const float4v o0 = *(const float4v*)(Om + p * C_ + lane * 8);
    const float4v o1 = *(const float4v*)(Om + p * C_ + lane * 8 + 4);
    const short8v qv = *(const short8v*)(qbf + p * C_ + lane * 8);
    float sum = 0.f, ssq = 0.f;
    #pragma unroll
    for (int j = 0; j < 8; ++j) {
        const float ov = (j < 4) ? o0[j] : o1[j - 4];
        const float v = ov + bf2f(((const ushort_t*)&qv)[j]);
        sum += v; ssq += v * v;
    }
    #pragma unroll
    for (int off = 32; off > 0; off >>= 1) {
        sum += __shfl_xor(sum, off, 64);
        ssq += __shfl_xor(ssq, off, 64);
    }
    if (lane == 0) {
        const float mean = sum * (1.f / 512.f);
        float var = (ssq - sum * mean) * (1.f / 511.f);
        var = var > 0.f ? var : 0.f;
        stats[p * 2] = mean;
        stats[p * 2 + 1] = 1.f / (sqrtf(var) + EPS_);
    }
}

// ---------------------------------------------------------------------------
// LN pass 2: normalize + gamma/beta, LDS-transposed write to (N,T,C,H,W).
// Block = (nt, 64-channel tile).
// ---------------------------------------------------------------------------
__global__ __launch_bounds__(256) void ln_write_kernel(
    const float* __restrict__ Om, const ushort_t* __restrict__ qbf,
    const float* __restrict__ stats, const float* __restrict__ gamma,
    const float* __restrict__ beta, float* __restrict__ out)
{
    __shared__ float Tl[64][197];
    const int nt = blockIdx.x;
    const int ct = blockIdx.y;
    const int tid = threadIdx.x;
    const int c = tid & 63;
    const float g = gamma[ct * 64 + c];
    const float bt = beta[ct * 64 + c];

    #pragma unroll 7
    for (int i = 0; i < 49; ++i) {
        const int e = i * 256 + tid;
        const int hw = e >> 6;
        const long p = (long)nt * HW_ + hw;
        const float mean = stats[p * 2];
        const float inv = stats[p * 2 + 1];
        const float x = Om[p * C_ + ct * 64 + c] + bf2f(qbf[p * C_ + ct * 64 + c]);
        Tl[c][hw] = g * (x - mean) * inv + bt;
    }
    __syncthreads();
    const long obase = ((long)nt * C_ + ct * 64) * HW_;
    #pragma unroll 7
    for (int i = 0; i < 49; ++i) {
        const int e = i * 256 + tid;
        const int cl = e / HW_;
        const int hw = e - cl * HW_;
        out[obase + (long)cl * HW_ + hw] = Tl[cl][hw];
    }
}

extern "C" void kernel_launch(void* const* d_in, const int* in_sizes, int n_in,
                              void* d_out, int out_size, void* d_ws, size_t ws_size,
                              hipStream_t stream) {
    const float* q_in  = (const float*)d_in[0];
    const float* k_in  = (const float*)d_in[1];
    const float* v_in  = (const float*)d_in[2];
    const float* Wq    = (const float*)d_in[3];
    const float* bq    = (const float*)d_in[4];
    const float* Wk    = (const float*)d_in[5];
    const float* bk    = (const float*)d_in[6];
    const float* Wv    = (const float*)d_in[7];
    const float* bv    = (const float*)d_in[8];
    const float* gamma = (const float*)d_in[9];
    const float* beta  = (const float*)d_in[10];
    float* out = (float*)d_out;

    const size_t PC = (size_t)P_TOT * C_;        // 3,211,264
    ushort_t* qbf = (ushort_t*)d_ws;
    ushort_t* kbf = qbf + PC;
    ushort_t* vbf = kbf + PC;
    ushort_t* Wbf = vbf + PC;                    // 3 x 512 x 512
    ushort_t* Qh  = Wbf + 3 * (size_t)C_ * C_;
    ushort_t* Kh  = Qh + PC;
    ushort_t* Vt  = Kh + PC;
    float* Om    = (float*)(Vt + PC);
    float* stats = Om + PC;
    float* qm    = stats + 2 * P_TOT;
    float* km    = qm + P_TOT;

    transpose_kernel<<<dim3(32, 8, 3), 256, 0, stream>>>(q_in, k_in, v_in, qbf, kbf, vbf);
    wconv_kernel<<<dim3(1024, 3), 256, 0, stream>>>(Wq, Wk, Wv, Wbf);
    mask_kernel<<<P_TOT / 4, 256, 0, stream>>>(qbf, kbf, qm, km);
    proj_mfma<0><<<dim3(49, 8), 256, 0, stream>>>(qbf, Wbf,                bq, Qh);
    proj_mfma<0><<<dim3(49, 8), 256, 0, stream>>>(kbf, Wbf + (size_t)C_ * C_, bk, Kh);
    proj_mfma<1><<<dim3(49, 8), 256, 0, stream>>>(vbf, Wbf + 2 * (size_t)C_ * C_, bv, Vt);
    attn_kernel<<<dim3(25, 32), 256, 0, stream>>>(Qh, Kh, Vt, km, qm, Om);
    ln_stats_kernel<<<P_TOT / 4, 256, 0, stream>>>(Om, qbf, stats);
    ln_write_kernel<<<dim3(32, 8), 256, 0, stream>>>(Om, qbf, stats, gamma, beta, out);
}

// Round 4
// 198.751 us; speedup vs baseline: 11.7928x; 1.1965x over previous
//
#include <hip/hip_runtime.h>
#include <math.h>

#define N_ 4
#define T_ 8
#define C_ 512
#define H_ 14
#define W_ 14
#define HEADS_ 8
#define D_ 64
#define HW_ 196
#define S_ 1568
#define P_TOT 6272
#define NEG_ (-4294967295.0f)
#define EPS_ 1e-8f

typedef __attribute__((ext_vector_type(8))) short short8v;
typedef __attribute__((ext_vector_type(4))) float float4v;
typedef __attribute__((ext_vector_type(4))) unsigned short ushort4v;
typedef unsigned short ushort_t;

__device__ __forceinline__ ushort_t f2bf(float f) {
    union { float f; unsigned u; } a; a.f = f;
    unsigned r = (a.u + 0x7FFFu + ((a.u >> 16) & 1u)) >> 16;
    return (ushort_t)r;
}
__device__ __forceinline__ float bf2f(ushort_t u) {
    union { unsigned u; float f; } t; t.u = ((unsigned)u) << 16; return t.f;
}
__device__ __forceinline__ unsigned cvt_pk_bf16(float lo, float hi) {
    unsigned r;
    asm("v_cvt_pk_bf16_f32 %0, %1, %2" : "=v"(r) : "v"(lo), "v"(hi));
    return r;
}

__device__ __forceinline__ float4v mfma16(short8v a, short8v b, float4v c) {
    return __builtin_amdgcn_mfma_f32_16x16x32_bf16(a, b, c, 0, 0, 0);
}

// ---------------------------------------------------------------------------
// Transpose pre-pass: (N,T,C,H,W) fp32 -> [p][c] bf16  (p = nt*196 + hw)
// ---------------------------------------------------------------------------
__global__ __launch_bounds__(256) void transpose_kernel(
    const float* __restrict__ q_in, const float* __restrict__ k_in,
    const float* __restrict__ v_in, ushort_t* __restrict__ qbf,
    ushort_t* __restrict__ kbf, ushort_t* __restrict__ vbf)
{
    __shared__ float Xs[64][197];
    const int z = blockIdx.z;
    const float* src = (z == 0) ? q_in : (z == 1) ? k_in : v_in;
    ushort_t* dst = (z == 0) ? qbf : (z == 1) ? kbf : vbf;

    const int nt = blockIdx.x;
    const int ct = blockIdx.y;
    const int tid = threadIdx.x;

    const long gbase = ((long)nt * C_ + ct * 64) * HW_;
    {
        int row = tid / HW_;
        int hw = tid - row * HW_;
        #pragma unroll 7
        for (int i = 0; i < 49; ++i) {
            Xs[row][hw] = src[gbase + i * 256 + tid];
            hw += 60; ++row;
            if (hw >= HW_) { hw -= HW_; ++row; }
        }
    }
    __syncthreads();
    {
        const int c = tid & 63;
        int hw = tid >> 6;
        #pragma unroll 7
        for (int i = 0; i < 49; ++i, hw += 4) {
            dst[((long)nt * HW_ + hw) * C_ + ct * 64 + c] = f2bf(Xs[c][hw]);
        }
    }
}

// ---------------------------------------------------------------------------
// Weight convert fp32 -> bf16
// ---------------------------------------------------------------------------
__global__ __launch_bounds__(256) void wconv_kernel(
    const float* __restrict__ Wq, const float* __restrict__ Wk,
    const float* __restrict__ Wv, ushort_t* __restrict__ Wbf)
{
    const int z = blockIdx.y;
    const float* src = (z == 0) ? Wq : (z == 1) ? Wk : Wv;
    const int idx = blockIdx.x * 256 + threadIdx.x;
    Wbf[(long)z * 262144 + idx] = f2bf(src[idx]);
}

// ---------------------------------------------------------------------------
// Padding masks (coalesced from bf16 copies)
// ---------------------------------------------------------------------------
__global__ __launch_bounds__(256) void mask_kernel(
    const ushort_t* __restrict__ qbf, const ushort_t* __restrict__ kbf,
    float* __restrict__ qm, float* __restrict__ km)
{
    const int tid = threadIdx.x;
    const int w = tid >> 6, lane = tid & 63;
    const int p = blockIdx.x * 4 + w;
    const short8v qv = *(const short8v*)(qbf + (long)p * C_ + lane * 8);
    const short8v kv = *(const short8v*)(kbf + (long)p * C_ + lane * 8);
    float sq = 0.f, sk = 0.f;
    #pragma unroll
    for (int j = 0; j < 8; ++j) {
        sq += bf2f(((const ushort_t*)&qv)[j]);
        sk += bf2f(((const ushort_t*)&kv)[j]);
    }
    #pragma unroll
    for (int off = 32; off > 0; off >>= 1) {
        sq += __shfl_xor(sq, off, 64);
        sk += __shfl_xor(sk, off, 64);
    }
    if (lane == 0) {
        qm[p] = (sq != 0.f) ? 1.f : 0.f;
        km[p] = (sk != 0.f) ? 1.f : 0.f;
    }
}

// ---------------------------------------------------------------------------
// MFMA projection, 2-phase double-buffered K-loop.
// TRANS=0: out[b][s][d] (Q,K).  TRANS=1: out[b][d][s] (V^T).
// ---------------------------------------------------------------------------
template <int TRANS>
__global__ __launch_bounds__(256) void proj_mfma(
    const ushort_t* __restrict__ Xbf, const ushort_t* __restrict__ Wbf,
    const float* __restrict__ bias, ushort_t* __restrict__ outp)
{
    __shared__ char lds[49152];   // 2 bufs x (16KB X + 8KB W)
    const int tid = threadIdx.x;
    const int w = tid >> 6, lane = tid & 63, lg = lane >> 4, lo = lane & 15;
    const int wr = w >> 1, wc = w & 1;
    const int p0 = blockIdx.x * 128;
    const int head = blockIdx.y;
    const int o0 = head * 64;

    float4v acc[2][4];
    #pragma unroll
    for (int a = 0; a < 2; ++a)
        #pragma unroll
        for (int b = 0; b < 4; ++b) acc[a][b] = (float4v){0.f, 0.f, 0.f, 0.f};

    uint4 xs[4], wsv[2];
    auto issue = [&](int k0) {
        #pragma unroll
        for (int i = 0; i < 4; ++i) {
            const int sl = tid + i * 256;
            const int row = sl >> 3, sir = sl & 7;
            const int c16 = sir ^ (row & 7);
            xs[i] = *(const uint4*)(Xbf + (long)(p0 + row) * C_ + k0 + c16 * 8);
        }
        #pragma unroll
        for (int i = 0; i < 2; ++i) {
            const int sl = tid + i * 256;
            const int row = sl >> 3, sir = sl & 7;
            const int c16 = sir ^ (row & 7);
            wsv[i] = *(const uint4*)(Wbf + (long)(o0 + row) * C_ + k0 + c16 * 8);
        }
    };
    auto commit = [&](int buf) {
        char* Xl = lds + buf * 24576;
        char* Wl = Xl + 16384;
        #pragma unroll
        for (int i = 0; i < 4; ++i) *(uint4*)(Xl + (tid + i * 256) * 16) = xs[i];
        #pragma unroll
        for (int i = 0; i < 2; ++i) *(uint4*)(Wl + (tid + i * 256) * 16) = wsv[i];
    };

    issue(0);
    commit(0);
    __syncthreads();
    int cur = 0;

    for (int kstep = 0; kstep < 8; ++kstep) {
        if (kstep < 7) issue((kstep + 1) * 64);

        char* Xl = lds + cur * 24576;
        char* Wl = Xl + 16384;
        short8v wf[2][2], xf[4][2];
        #pragma unroll
        for (int a = 0; a < 2; ++a) {
            const int row = wc * 32 + a * 16 + lo;
            const int swr = (row & 7) << 4;
            #pragma unroll
            for (int ks = 0; ks < 2; ++ks) {
                const int base = row * 128 + ks * 64 + lg * 8;
                ((uint2*)&wf[a][ks])[0] = *(const uint2*)(Wl + (base ^ swr));
                ((uint2*)&wf[a][ks])[1] = *(const uint2*)(Wl + ((base + 32) ^ swr));
            }
        }
        #pragma unroll
        for (int b = 0; b < 4; ++b) {
            const int row = wr * 64 + b * 16 + lo;
            const int swr = (row & 7) << 4;
            #pragma unroll
            for (int ks = 0; ks < 2; ++ks) {
                const int base = row * 128 + ks * 64 + lg * 8;
                ((uint2*)&xf[b][ks])[0] = *(const uint2*)(Xl + (base ^ swr));
                ((uint2*)&xf[b][ks])[1] = *(const uint2*)(Xl + ((base + 32) ^ swr));
            }
        }
        #pragma unroll
        for (int ks = 0; ks < 2; ++ks)
            #pragma unroll
            for (int a = 0; a < 2; ++a)
                #pragma unroll
                for (int b = 0; b < 4; ++b)
                    acc[a][b] = TRANS ? mfma16(xf[b][ks], wf[a][ks], acc[a][b])
                                      : mfma16(wf[a][ks], xf[b][ks], acc[a][b]);

        if (kstep < 7) commit(cur ^ 1);
        __syncthreads();
        cur ^= 1;
    }

    if (TRANS == 0) {
        #pragma unroll
        for (int b = 0; b < 4; ++b) {
            const int p = p0 + wr * 64 + b * 16 + lo;
            const int nb = p / S_;
            const int s = p - nb * S_;
            #pragma unroll
            for (int a = 0; a < 2; ++a) {
                const int d0 = wc * 32 + a * 16 + lg * 4;
                const float4v bs = *(const float4v*)(bias + o0 + d0);
                ushort4v pk;
                #pragma unroll
                for (int e = 0; e < 4; ++e) {
                    float v = acc[a][b][e] + bs[e];
                    v = v > 0.f ? v : 0.f;
                    pk[e] = f2bf(v);
                }
                *(ushort4v*)(outp + ((long)(head * N_ + nb) * S_ + s) * D_ + d0) = pk;
            }
        }
    } else {
        #pragma unroll
        for (int a = 0; a < 2; ++a) {
            const int d = wc * 32 + a * 16 + lo;
            const float bsc = bias[o0 + d];
            #pragma unroll
            for (int b = 0; b < 4; ++b) {
                const int pb = p0 + wr * 64 + b * 16 + lg * 4;
                const int nb = pb / S_;
                const int s0 = pb - nb * S_;
                ushort4v pk;
                #pragma unroll
                for (int e = 0; e < 4; ++e) {
                    float v = acc[a][b][e] + bsc;
                    v = v > 0.f ? v : 0.f;
                    pk[e] = f2bf(v);
                }
                *(ushort4v*)(outp + ((long)(head * N_ + nb) * D_ + d) * S_ + s0) = pk;
            }
        }
    }
}

// ---------------------------------------------------------------------------
// MFMA flash attention: double-buffered prefetch, additive mask bias,
// defer-max (exact), cvt_pk bf16 pack, setprio, XCD-aware block decode.
// ---------------------------------------------------------------------------
__global__ __launch_bounds__(256) void attn_kernel(
    const ushort_t* __restrict__ Qh, const ushort_t* __restrict__ Kh,
    const ushort_t* __restrict__ Vt, const float* __restrict__ km,
    const float* __restrict__ qm, float* __restrict__ Om)
{
    __shared__ char lds[2 * 16384 + 2 * 256];   // per buf: K 8KB, V 8KB; kms 256B

    const int tid = threadIdx.x;
    const int lane = tid & 63;
    const int w = tid >> 6;
    const int lg = lane >> 4;
    const int lo = lane & 15;

    // XCD-aware decode: all 25 q-tiles of a b-group land on one XCD.
    const int fid = blockIdx.x;          // 0..799
    const int x = fid & 7;
    const int j = fid >> 3;              // 0..99
    const int b = x + 8 * (j / 25);
    const int q0 = (j % 25) * 64;
    const int n = b & (N_ - 1);
    const int head = b >> 2;

    const int qrow = q0 + w * 16 + lo;
    const int qcl = qrow < S_ ? qrow : S_ - 1;
    const ushort_t* qp = Qh + ((long)b * S_ + qcl) * D_ + lg * 4;
    short8v qf[2];
    #pragma unroll
    for (int ks = 0; ks < 2; ++ks) {
        ((uint2*)&qf[ks])[0] = *(const uint2*)(qp + ks * 32);
        ((uint2*)&qf[ks])[1] = *(const uint2*)(qp + ks * 32 + 16);
    }

    float4v acc[4];
    #pragma unroll
    for (int dt = 0; dt < 4; ++dt) acc[dt] = (float4v){0.f, 0.f, 0.f, 0.f};
    float m_run = -INFINITY, l_run = 0.f;

    const int sr = tid >> 2;
    const int sseg = tid & 3;
    const int sw = (sr & 7) << 4;
    const int kbase = sr * 128 + sseg * 32;

    uint4 kv0, kv1, vv0, vv1;
    float kmb = 0.f;
    auto issue = [&](int kb) {
        int krow = kb + sr; if (krow >= S_) krow = S_ - 1;
        const uint4* kg = (const uint4*)(Kh + ((long)b * S_ + krow) * D_ + sseg * 16);
        kv0 = kg[0]; kv1 = kg[1];
        int c0 = kb + sseg * 16; if (c0 > S_ - 16) c0 = S_ - 16;
        const uint4* vg = (const uint4*)(Vt + ((long)b * D_ + sr) * S_ + c0);
        vv0 = vg[0]; vv1 = vg[1];
        if (tid < 64) {
            const int kr = kb + tid;
            kmb = (kr < S_ && km[n * S_ + kr] != 0.f) ? 0.f : NEG_;
        }
    };
    auto commit = [&](int buf) {
        char* Kl = lds + buf * 16384;
        char* Vl = Kl + 8192;
        float* kmsb = (float*)(lds + 32768 + buf * 256);
        *(uint4*)(Kl + (kbase ^ sw)) = kv0;
        *(uint4*)(Kl + ((kbase + 16) ^ sw)) = kv1;
        *(uint4*)(Vl + (kbase ^ sw)) = vv0;
        *(uint4*)(Vl + ((kbase + 16) ^ sw)) = vv1;
        if (tid < 64) kmsb[tid] = kmb;
    };

    issue(0);
    commit(0);
    __syncthreads();
    int cur = 0;

    const int NT = (S_ + 63) / 64;   // 25
    for (int t = 0; t < NT; ++t) {
        const bool has_next = (t + 1) < NT;
        if (has_next) issue((t + 1) * 64);

        char* Kl = lds + cur * 16384;
        char* Vl = Kl + 8192;
        const float* kmsb = (const float*)(lds + 32768 + cur * 256);

        // ---- QK^T (swapped): s[kt] rows = k, cols = wave's 16 q ----
        float4v s[4];
        __builtin_amdgcn_s_setprio(1);
        #pragma unroll
        for (int kt = 0; kt < 4; ++kt) {
            s[kt] = (float4v){0.f, 0.f, 0.f, 0.f};
            #pragma unroll
            for (int ks = 0; ks < 2; ++ks) {
                const int row = kt * 16 + lo;
                const int base = row * 128 + ks * 64 + lg * 8;
                const int swr = (row & 7) << 4;
                short8v kf;
                ((uint2*)&kf)[0] = *(const uint2*)(Kl + (base ^ swr));
                ((uint2*)&kf)[1] = *(const uint2*)(Kl + ((base + 32) ^ swr));
                s[kt] = mfma16(kf, qf[ks], s[kt]);
            }
        }
        __builtin_amdgcn_s_setprio(0);

        // ---- online softmax: mask as additive bias, defer-max (exact) ----
        float p[4][4];
        float mx = -INFINITY;
        #pragma unroll
        for (int kt = 0; kt < 4; ++kt) {
            const float4v bv4 = *(const float4v*)&kmsb[kt * 16 + lg * 4];
            #pragma unroll
            for (int r = 0; r < 4; ++r) {
                const float sm = fmaf(s[kt][r], 0.125f, bv4[r]);
                p[kt][r] = sm;
                mx = fmaxf(mx, sm);
            }
        }
        mx = fmaxf(mx, __shfl_xor(mx, 16, 64));
        mx = fmaxf(mx, __shfl_xor(mx, 32, 64));
        float mn;
        if (__all(mx <= m_run + 8.f)) {
            mn = m_run;                      // defer: keep old max (exact)
        } else {
            mn = fmaxf(m_run, mx);
            const float alpha = __expf(m_run - mn);
            m_run = mn;
            l_run *= alpha;
            #pragma unroll
            for (int dt = 0; dt < 4; ++dt)
                #pragma unroll
                for (int r = 0; r < 4; ++r) acc[dt][r] *= alpha;
        }
        float rs = 0.f;
        #pragma unroll
        for (int kt = 0; kt < 4; ++kt)
            #pragma unroll
            for (int r = 0; r < 4; ++r) {
                const float pv = __expf(p[kt][r] - mn);
                p[kt][r] = pv;
                rs += pv;
            }
        rs += __shfl_xor(rs, 16, 64);
        rs += __shfl_xor(rs, 32, 64);
        l_run += rs;

        // ---- pack P to bf16 via v_cvt_pk_bf16_f32 ----
        short8v pf[2];
        #pragma unroll
        for (int kt = 0; kt < 4; ++kt) {
            const unsigned w0 = cvt_pk_bf16(p[kt][0], p[kt][1]);
            const unsigned w1 = cvt_pk_bf16(p[kt][2], p[kt][3]);
            ((unsigned*)&pf[kt >> 1])[(kt & 1) * 2] = w0;
            ((unsigned*)&pf[kt >> 1])[(kt & 1) * 2 + 1] = w1;
        }

        // ---- PV: out^T += V^T . P^T ----
        __builtin_amdgcn_s_setprio(1);
        #pragma unroll
        for (int dt = 0; dt < 4; ++dt) {
            #pragma unroll
            for (int ks = 0; ks < 2; ++ks) {
                const int row = dt * 16 + lo;
                const int base = row * 128 + ks * 64 + lg * 8;
                const int swr = (row & 7) << 4;
                short8v vf;
                ((uint2*)&vf)[0] = *(const uint2*)(Vl + (base ^ swr));
                ((uint2*)&vf)[1] = *(const uint2*)(Vl + ((base + 32) ^ swr));
                acc[dt] = mfma16(vf, pf[ks], acc[dt]);
            }
        }
        __builtin_amdgcn_s_setprio(0);

        if (has_next) commit(cur ^ 1);
        __syncthreads();
        cur ^= 1;
    }

    if (qrow < S_) {
        const float inv = qm[n * S_ + qrow] / l_run;
        float* dst = Om + ((long)n * S_ + qrow) * C_ + head * D_;
        #pragma unroll
        for (int dt = 0; dt < 4; ++dt) {
            float4v o;
            #pragma unroll
            for (int r = 0; r < 4; ++r) o[r] = acc[dt][r] * inv;
            *(float4v*)(dst + dt * 16 + lg * 4) = o;
        }
    }
}

// ---------------------------------------------------------------------------
// LN pass 1: per-position mean and 1/(std+eps)
// ---------------------------------------------------------------------------
__global__ __launch_bounds__(256) void ln_stats_kernel(
    const float* __restrict__ Om, const ushort_t* __restrict__ qbf,
    float* __restrict__ stats)
{
    const int tid = threadIdx.x;
    const int w = tid >> 6, lane = tid & 63;
    const long p = blockIdx.x * 4 + w;
    const float4v o0 = *(const float4v*)(Om + p * C_ + lane * 8);
    const float4v o1 = *(const float4v*)(Om + p * C_ + lane * 8 + 4);
    const short8v qv = *(const short8v*)(qbf + p * C_ + lane * 8);
    float sum = 0.f, ssq = 0.f;
    #pragma unroll
    for (int j = 0; j < 8; ++j) {
        const float ov = (j < 4) ? o0[j] : o1[j - 4];
        const float v = ov + bf2f(((const ushort_t*)&qv)[j]);
        sum += v; ssq += v * v;
    }
    #pragma unroll
    for (int off = 32; off > 0; off >>= 1) {
        sum += __shfl_xor(sum, off, 64);
        ssq += __shfl_xor(ssq, off, 64);
    }
    if (lane == 0) {
        const float mean = sum * (1.f / 512.f);
        float var = (ssq - sum * mean) * (1.f / 511.f);
        var = var > 0.f ? var : 0.f;
        stats[p * 2] = mean;
        stats[p * 2 + 1] = 1.f / (sqrtf(var) + EPS_);
    }
}

// ---------------------------------------------------------------------------
// LN pass 2: normalize + gamma/beta, LDS-transposed write to (N,T,C,H,W)
// ---------------------------------------------------------------------------
__global__ __launch_bounds__(256) void ln_write_kernel(
    const float* __restrict__ Om, const ushort_t* __restrict__ qbf,
    const float* __restrict__ stats, const float* __restrict__ gamma,
    const float* __restrict__ beta, float* __restrict__ out)
{
    __shared__ float Tl[64][197];
    const int nt = blockIdx.x;
    const int ct = blockIdx.y;
    const int tid = threadIdx.x;
    const int c = tid & 63;
    const float g = gamma[ct * 64 + c];
    const float bt = beta[ct * 64 + c];

    {
        int hw = tid >> 6;
        #pragma unroll 7
        for (int i = 0; i < 49; ++i, hw += 4) {
            const long p = (long)nt * HW_ + hw;
            const float mean = stats[p * 2];
            const float inv = stats[p * 2 + 1];
            const float xv = Om[p * C_ + ct * 64 + c] + bf2f(qbf[p * C_ + ct * 64 + c]);
            Tl[c][hw] = g * (xv - mean) * inv + bt;
        }
    }
    __syncthreads();
    {
        const long obase = ((long)nt * C_ + ct * 64) * HW_;
        int cl = tid / HW_;
        int hw = tid - cl * HW_;
        #pragma unroll 7
        for (int i = 0; i < 49; ++i) {
            out[obase + i * 256 + tid] = Tl[cl][hw];
            hw += 60; ++cl;
            if (hw >= HW_) { hw -= HW_; ++cl; }
        }
    }
}

extern "C" void kernel_launch(void* const* d_in, const int* in_sizes, int n_in,
                              void* d_out, int out_size, void* d_ws, size_t ws_size,
                              hipStream_t stream) {
    const float* q_in  = (const float*)d_in[0];
    const float* k_in  = (const float*)d_in[1];
    const float* v_in  = (const float*)d_in[2];
    const float* Wq    = (const float*)d_in[3];
    const float* bq    = (const float*)d_in[4];
    const float* Wk    = (const float*)d_in[5];
    const float* bk    = (const float*)d_in[6];
    const float* Wv    = (const float*)d_in[7];
    const float* bv    = (const float*)d_in[8];
    const float* gamma = (const float*)d_in[9];
    const float* beta  = (const float*)d_in[10];
    float* out = (float*)d_out;

    const size_t PC = (size_t)P_TOT * C_;
    ushort_t* qbf = (ushort_t*)d_ws;
    ushort_t* kbf = qbf + PC;
    ushort_t* vbf = kbf + PC;
    ushort_t* Wbf = vbf + PC;
    ushort_t* Qh  = Wbf + 3 * (size_t)C_ * C_;
    ushort_t* Kh  = Qh + PC;
    ushort_t* Vt  = Kh + PC;
    float* Om    = (float*)(Vt + PC);
    float* stats = Om + PC;
    float* qm    = stats + 2 * P_TOT;
    float* km    = qm + P_TOT;

    transpose_kernel<<<dim3(32, 8, 3), 256, 0, stream>>>(q_in, k_in, v_in, qbf, kbf, vbf);
    wconv_kernel<<<dim3(1024, 3), 256, 0, stream>>>(Wq, Wk, Wv, Wbf);
    mask_kernel<<<P_TOT / 4, 256, 0, stream>>>(qbf, kbf, qm, km);
    proj_mfma<0><<<dim3(49, 8), 256, 0, stream>>>(qbf, Wbf,                       bq, Qh);
    proj_mfma<0><<<dim3(49, 8), 256, 0, stream>>>(kbf, Wbf + (size_t)C_ * C_,     bk, Kh);
    proj_mfma<1><<<dim3(49, 8), 256, 0, stream>>>(vbf, Wbf + 2 * (size_t)C_ * C_, bv, Vt);
    attn_kernel<<<800, 256, 0, stream>>>(Qh, Kh, Vt, km, qm, Om);
    ln_stats_kernel<<<P_TOT / 4, 256, 0, stream>>>(Om, qbf, stats);
    ln_write_kernel<<<dim3(32, 8), 256, 0, stream>>>(Om, qbf, stats, gamma, beta, out);
}

// Round 5
// 143.363 us; speedup vs baseline: 16.3490x; 1.3864x over previous
//
#include <hip/hip_runtime.h>
#include <math.h>

#define N_ 4
#define T_ 8
#define C_ 512
#define H_ 14
#define W_ 14
#define HEADS_ 8
#define D_ 64
#define HW_ 196
#define S_ 1568
#define P_TOT 6272
#define NEG_ (-4294967295.0f)
#define EPS_ 1e-8f
#define SPLIT_T_ 12     // kv tiles [0,12) vs [12,25)

typedef __attribute__((ext_vector_type(8))) short short8v;
typedef __attribute__((ext_vector_type(4))) float float4v;
typedef __attribute__((ext_vector_type(4))) unsigned short ushort4v;
typedef unsigned short ushort_t;

__device__ __forceinline__ ushort_t f2bf(float f) {
    union { float f; unsigned u; } a; a.f = f;
    unsigned r = (a.u + 0x7FFFu + ((a.u >> 16) & 1u)) >> 16;
    return (ushort_t)r;
}
__device__ __forceinline__ float bf2f(ushort_t u) {
    union { unsigned u; float f; } t; t.u = ((unsigned)u) << 16; return t.f;
}
__device__ __forceinline__ unsigned cvt_pk_bf16(float lo, float hi) {
    unsigned r;
    asm("v_cvt_pk_bf16_f32 %0, %1, %2" : "=v"(r) : "v"(lo), "v"(hi));
    return r;
}
__device__ __forceinline__ float4v mfma16(short8v a, short8v b, float4v c) {
    return __builtin_amdgcn_mfma_f32_16x16x32_bf16(a, b, c, 0, 0, 0);
}

// ---------------------------------------------------------------------------
// Transpose pre-pass: (N,T,C,H,W) fp32 -> [p][c] bf16. float4 reads, ushort4
// writes (G13). LDS pad 197 keeps both phases ~2-way on banks.
// ---------------------------------------------------------------------------
__global__ __launch_bounds__(256) void transpose_kernel(
    const float* __restrict__ q_in, const float* __restrict__ k_in,
    const float* __restrict__ v_in, ushort_t* __restrict__ qbf,
    ushort_t* __restrict__ kbf, ushort_t* __restrict__ vbf)
{
    __shared__ float Xs[64][197];
    const int z = blockIdx.z;
    const float* src = (z == 0) ? q_in : (z == 1) ? k_in : v_in;
    ushort_t* dst = (z == 0) ? qbf : (z == 1) ? kbf : vbf;

    const int nt = blockIdx.x;
    const int ct = blockIdx.y;
    const int tid = threadIdx.x;

    const long gbase = ((long)nt * C_ + ct * 64) * HW_;
    #pragma unroll
    for (int i = 0; i < 13; ++i) {
        const int idx = i * 256 + tid;          // 3136 float4 quads
        if (idx < 3136) {
            const int c = idx / 49;
            const int q4 = idx - c * 49;
            const float4 v = *(const float4*)(src + gbase + c * HW_ + q4 * 4);
            Xs[c][q4 * 4 + 0] = v.x;
            Xs[c][q4 * 4 + 1] = v.y;
            Xs[c][q4 * 4 + 2] = v.z;
            Xs[c][q4 * 4 + 3] = v.w;
        }
    }
    __syncthreads();
    const long pbase = (long)nt * HW_;
    const int c0 = (tid & 15) * 4;               // constant per thread
    #pragma unroll
    for (int i = 0; i < 13; ++i) {
        const int idx = i * 256 + tid;
        if (idx < 3136) {
            const int hw = idx >> 4;
            ushort4v pk;
            #pragma unroll
            for (int e = 0; e < 4; ++e) pk[e] = f2bf(Xs[c0 + e][hw]);
            *(ushort4v*)(dst + (pbase + hw) * C_ + ct * 64 + c0) = pk;
        }
    }
}

// ---------------------------------------------------------------------------
// Padding masks (coalesced from bf16 copies)
// ---------------------------------------------------------------------------
__global__ __launch_bounds__(256) void mask_kernel(
    const ushort_t* __restrict__ qbf, const ushort_t* __restrict__ kbf,
    float* __restrict__ qm, float* __restrict__ km)
{
    const int tid = threadIdx.x;
    const int w = tid >> 6, lane = tid & 63;
    const int p = blockIdx.x * 4 + w;
    const short8v qv = *(const short8v*)(qbf + (long)p * C_ + lane * 8);
    const short8v kv = *(const short8v*)(kbf + (long)p * C_ + lane * 8);
    float sq = 0.f, sk = 0.f;
    #pragma unroll
    for (int j = 0; j < 8; ++j) {
        sq += bf2f(((const ushort_t*)&qv)[j]);
        sk += bf2f(((const ushort_t*)&kv)[j]);
    }
    #pragma unroll
    for (int off = 32; off > 0; off >>= 1) {
        sq += __shfl_xor(sq, off, 64);
        sk += __shfl_xor(sk, off, 64);
    }
    if (lane == 0) {
        qm[p] = (sq != 0.f) ? 1.f : 0.f;
        km[p] = (sk != 0.f) ? 1.f : 0.f;
    }
}

// ---------------------------------------------------------------------------
// All three projections in ONE dispatch (z = 0 Q, 1 K, 2 V-transposed).
// W converted fp32->bf16 on the fly during staging. 2-phase double buffer.
// ---------------------------------------------------------------------------
__global__ __launch_bounds__(256) void proj_all(
    const ushort_t* __restrict__ qbf, const ushort_t* __restrict__ kbf,
    const ushort_t* __restrict__ vbf,
    const float* __restrict__ Wq, const float* __restrict__ Wk,
    const float* __restrict__ Wv,
    const float* __restrict__ bq, const float* __restrict__ bk,
    const float* __restrict__ bv,
    ushort_t* __restrict__ Qh, ushort_t* __restrict__ Kh,
    ushort_t* __restrict__ Vt)
{
    __shared__ char lds[49152];
    const int z = blockIdx.z;
    const ushort_t* Xbf = (z == 0) ? qbf : (z == 1) ? kbf : vbf;
    const float* Wm = (z == 0) ? Wq : (z == 1) ? Wk : Wv;
    const float* bias = (z == 0) ? bq : (z == 1) ? bk : bv;
    ushort_t* outp = (z == 0) ? Qh : (z == 1) ? Kh : Vt;
    const bool TR = (z == 2);

    const int tid = threadIdx.x;
    const int w = tid >> 6, lane = tid & 63, lg = lane >> 4, lo = lane & 15;
    const int wr = w >> 1, wc = w & 1;
    const int p0 = blockIdx.x * 128;
    const int head = blockIdx.y;
    const int o0 = head * 64;

    float4v acc[2][4];
    #pragma unroll
    for (int a = 0; a < 2; ++a)
        #pragma unroll
        for (int b = 0; b < 4; ++b) acc[a][b] = (float4v){0.f, 0.f, 0.f, 0.f};

    uint4 xs[4], wsv[2];
    auto issue = [&](int k0) {
        #pragma unroll
        for (int i = 0; i < 4; ++i) {
            const int sl = tid + i * 256;
            const int row = sl >> 3, sir = sl & 7;
            const int c16 = sir ^ (row & 7);
            xs[i] = *(const uint4*)(Xbf + (long)(p0 + row) * C_ + k0 + c16 * 8);
        }
        #pragma unroll
        for (int i = 0; i < 2; ++i) {
            const int sl = tid + i * 256;
            const int row = sl >> 3, sir = sl & 7;
            const int c16 = sir ^ (row & 7);
            const float* wp = Wm + (long)(o0 + row) * C_ + k0 + c16 * 8;
            const float4 a4 = *(const float4*)(wp);
            const float4 b4 = *(const float4*)(wp + 4);
            wsv[i].x = cvt_pk_bf16(a4.x, a4.y);
            wsv[i].y = cvt_pk_bf16(a4.z, a4.w);
            wsv[i].z = cvt_pk_bf16(b4.x, b4.y);
            wsv[i].w = cvt_pk_bf16(b4.z, b4.w);
        }
    };
    auto commit = [&](int buf) {
        char* Xl = lds + buf * 24576;
        char* Wl = Xl + 16384;
        #pragma unroll
        for (int i = 0; i < 4; ++i) *(uint4*)(Xl + (tid + i * 256) * 16) = xs[i];
        #pragma unroll
        for (int i = 0; i < 2; ++i) *(uint4*)(Wl + (tid + i * 256) * 16) = wsv[i];
    };

    issue(0);
    commit(0);
    __syncthreads();
    int cur = 0;

    for (int kstep = 0; kstep < 8; ++kstep) {
        if (kstep < 7) issue((kstep + 1) * 64);

        char* Xl = lds + cur * 24576;
        char* Wl = Xl + 16384;
        short8v wf[2][2], xf[4][2];
        #pragma unroll
        for (int a = 0; a < 2; ++a) {
            const int row = wc * 32 + a * 16 + lo;
            const int swr = (row & 7) << 4;
            #pragma unroll
            for (int ks = 0; ks < 2; ++ks) {
                const int base = row * 128 + ks * 64 + lg * 8;
                ((uint2*)&wf[a][ks])[0] = *(const uint2*)(Wl + (base ^ swr));
                ((uint2*)&wf[a][ks])[1] = *(const uint2*)(Wl + ((base + 32) ^ swr));
            }
        }
        #pragma unroll
        for (int b = 0; b < 4; ++b) {
            const int row = wr * 64 + b * 16 + lo;
            const int swr = (row & 7) << 4;
            #pragma unroll
            for (int ks = 0; ks < 2; ++ks) {
                const int base = row * 128 + ks * 64 + lg * 8;
                ((uint2*)&xf[b][ks])[0] = *(const uint2*)(Xl + (base ^ swr));
                ((uint2*)&xf[b][ks])[1] = *(const uint2*)(Xl + ((base + 32) ^ swr));
            }
        }
        if (!TR) {
            #pragma unroll
            for (int ks = 0; ks < 2; ++ks)
                #pragma unroll
                for (int a = 0; a < 2; ++a)
                    #pragma unroll
                    for (int b = 0; b < 4; ++b)
                        acc[a][b] = mfma16(wf[a][ks], xf[b][ks], acc[a][b]);
        } else {
            #pragma unroll
            for (int ks = 0; ks < 2; ++ks)
                #pragma unroll
                for (int a = 0; a < 2; ++a)
                    #pragma unroll
                    for (int b = 0; b < 4; ++b)
                        acc[a][b] = mfma16(xf[b][ks], wf[a][ks], acc[a][b]);
        }

        if (kstep < 7) commit(cur ^ 1);
        __syncthreads();
        cur ^= 1;
    }

    if (!TR) {
        #pragma unroll
        for (int b = 0; b < 4; ++b) {
            const int p = p0 + wr * 64 + b * 16 + lo;
            const int nb = p / S_;
            const int s = p - nb * S_;
            #pragma unroll
            for (int a = 0; a < 2; ++a) {
                const int d0 = wc * 32 + a * 16 + lg * 4;
                const float4v bs = *(const float4v*)(bias + o0 + d0);
                ushort4v pk;
                #pragma unroll
                for (int e = 0; e < 4; ++e) {
                    float v = acc[a][b][e] + bs[e];
                    v = v > 0.f ? v : 0.f;
                    pk[e] = f2bf(v);
                }
                *(ushort4v*)(outp + ((long)(head * N_ + nb) * S_ + s) * D_ + d0) = pk;
            }
        }
    } else {
        #pragma unroll
        for (int a = 0; a < 2; ++a) {
            const int d = wc * 32 + a * 16 + lo;
            const float bsc = bias[o0 + d];
            #pragma unroll
            for (int b = 0; b < 4; ++b) {
                const int pb = p0 + wr * 64 + b * 16 + lg * 4;
                const int nb = pb / S_;
                const int s0 = pb - nb * S_;
                ushort4v pk;
                #pragma unroll
                for (int e = 0; e < 4; ++e) {
                    float v = acc[a][b][e] + bsc;
                    v = v > 0.f ? v : 0.f;
                    pk[e] = f2bf(v);
                }
                *(ushort4v*)(outp + ((long)(head * N_ + nb) * D_ + d) * S_ + s0) = pk;
            }
        }
    }
}

// ---------------------------------------------------------------------------
// Split-K flash attention: blockIdx.y = kv split (tiles [0,12) / [12,25)).
// Writes unnormalized partials Pacc + (m,l) per (split, b, q). Combine kernel
// does the log-sum-exp merge, qm multiply, and 1/l normalization.
// ---------------------------------------------------------------------------
__global__ __launch_bounds__(256) void attn_kernel(
    const ushort_t* __restrict__ Qh, const ushort_t* __restrict__ Kh,
    const ushort_t* __restrict__ Vt, const float* __restrict__ km,
    float* __restrict__ Pacc, float* __restrict__ Ml)
{
    __shared__ char lds[2 * 16384 + 2 * 256];

    const int tid = threadIdx.x;
    const int lane = tid & 63;
    const int w = tid >> 6;
    const int lg = lane >> 4;
    const int lo = lane & 15;

    const int split = blockIdx.y;
    const int t0 = split ? SPLIT_T_ : 0;
    const int t1 = split ? 25 : SPLIT_T_;

    const int fid = blockIdx.x;          // 0..799, XCD-aware decode
    const int x = fid & 7;
    const int j = fid >> 3;
    const int b = x + 8 * (j / 25);
    const int q0 = (j % 25) * 64;
    const int n = b & (N_ - 1);

    const int qrow = q0 + w * 16 + lo;
    const int qcl = qrow < S_ ? qrow : S_ - 1;
    const ushort_t* qp = Qh + ((long)b * S_ + qcl) * D_ + lg * 4;
    short8v qf[2];
    #pragma unroll
    for (int ks = 0; ks < 2; ++ks) {
        ((uint2*)&qf[ks])[0] = *(const uint2*)(qp + ks * 32);
        ((uint2*)&qf[ks])[1] = *(const uint2*)(qp + ks * 32 + 16);
    }

    float4v acc[4];
    #pragma unroll
    for (int dt = 0; dt < 4; ++dt) acc[dt] = (float4v){0.f, 0.f, 0.f, 0.f};
    float m_run = -INFINITY, l_run = 0.f;

    const int sr = tid >> 2;
    const int sseg = tid & 3;
    const int sw = (sr & 7) << 4;
    const int kbase = sr * 128 + sseg * 32;

    uint4 kv0, kv1, vv0, vv1;
    float kmb = 0.f;
    auto issue = [&](int kb) {
        int krow = kb + sr; if (krow >= S_) krow = S_ - 1;
        const uint4* kg = (const uint4*)(Kh + ((long)b * S_ + krow) * D_ + sseg * 16);
        kv0 = kg[0]; kv1 = kg[1];
        int c0 = kb + sseg * 16; if (c0 > S_ - 16) c0 = S_ - 16;
        const uint4* vg = (const uint4*)(Vt + ((long)b * D_ + sr) * S_ + c0);
        vv0 = vg[0]; vv1 = vg[1];
        if (tid < 64) {
            const int kr = kb + tid;
            kmb = (kr < S_ && km[n * S_ + kr] != 0.f) ? 0.f : NEG_;
        }
    };
    auto commit = [&](int buf) {
        char* Kl = lds + buf * 16384;
        char* Vl = Kl + 8192;
        float* kmsb = (float*)(lds + 32768 + buf * 256);
        *(uint4*)(Kl + (kbase ^ sw)) = kv0;
        *(uint4*)(Kl + ((kbase + 16) ^ sw)) = kv1;
        *(uint4*)(Vl + (kbase ^ sw)) = vv0;
        *(uint4*)(Vl + ((kbase + 16) ^ sw)) = vv1;
        if (tid < 64) kmsb[tid] = kmb;
    };

    issue(t0 * 64);
    commit(0);
    __syncthreads();
    int cur = 0;

    for (int t = t0; t < t1; ++t) {
        const bool has_next = (t + 1) < t1;
        if (has_next) issue((t + 1) * 64);

        char* Kl = lds + cur * 16384;
        char* Vl = Kl + 8192;
        const float* kmsb = (const float*)(lds + 32768 + cur * 256);

        float4v s[4];
        __builtin_amdgcn_s_setprio(1);
        #pragma unroll
        for (int kt = 0; kt < 4; ++kt) {
            s[kt] = (float4v){0.f, 0.f, 0.f, 0.f};
            #pragma unroll
            for (int ks = 0; ks < 2; ++ks) {
                const int row = kt * 16 + lo;
                const int base = row * 128 + ks * 64 + lg * 8;
                const int swr = (row & 7) << 4;
                short8v kf;
                ((uint2*)&kf)[0] = *(const uint2*)(Kl + (base ^ swr));
                ((uint2*)&kf)[1] = *(const uint2*)(Kl + ((base + 32) ^ swr));
                s[kt] = mfma16(kf, qf[ks], s[kt]);
            }
        }
        __builtin_amdgcn_s_setprio(0);

        float p[4][4];
        float mx = -INFINITY;
        #pragma unroll
        for (int kt = 0; kt < 4; ++kt) {
            const float4v bv4 = *(const float4v*)&kmsb[kt * 16 + lg * 4];
            #pragma unroll
            for (int r = 0; r < 4; ++r) {
                const float sm = fmaf(s[kt][r], 0.125f, bv4[r]);
                p[kt][r] = sm;
                mx = fmaxf(mx, sm);
            }
        }
        mx = fmaxf(mx, __shfl_xor(mx, 16, 64));
        mx = fmaxf(mx, __shfl_xor(mx, 32, 64));
        float mn;
        if (__all(mx <= m_run + 8.f)) {
            mn = m_run;
        } else {
            mn = fmaxf(m_run, mx);
            const float alpha = __expf(m_run - mn);
            m_run = mn;
            l_run *= alpha;
            #pragma unroll
            for (int dt = 0; dt < 4; ++dt)
                #pragma unroll
                for (int r = 0; r < 4; ++r) acc[dt][r] *= alpha;
        }
        float rs = 0.f;
        #pragma unroll
        for (int kt = 0; kt < 4; ++kt)
            #pragma unroll
            for (int r = 0; r < 4; ++r) {
                const float pv = __expf(p[kt][r] - mn);
                p[kt][r] = pv;
                rs += pv;
            }
        rs += __shfl_xor(rs, 16, 64);
        rs += __shfl_xor(rs, 32, 64);
        l_run += rs;

        short8v pf[2];
        #pragma unroll
        for (int kt = 0; kt < 4; ++kt) {
            const unsigned w0 = cvt_pk_bf16(p[kt][0], p[kt][1]);
            const unsigned w1 = cvt_pk_bf16(p[kt][2], p[kt][3]);
            ((unsigned*)&pf[kt >> 1])[(kt & 1) * 2] = w0;
            ((unsigned*)&pf[kt >> 1])[(kt & 1) * 2 + 1] = w1;
        }

        __builtin_amdgcn_s_setprio(1);
        #pragma unroll
        for (int dt = 0; dt < 4; ++dt) {
            #pragma unroll
            for (int ks = 0; ks < 2; ++ks) {
                const int row = dt * 16 + lo;
                const int base = row * 128 + ks * 64 + lg * 8;
                const int swr = (row & 7) << 4;
                short8v vf;
                ((uint2*)&vf)[0] = *(const uint2*)(Vl + (base ^ swr));
                ((uint2*)&vf)[1] = *(const uint2*)(Vl + ((base + 32) ^ swr));
                acc[dt] = mfma16(vf, pf[ks], acc[dt]);
            }
        }
        __builtin_amdgcn_s_setprio(0);

        if (has_next) commit(cur ^ 1);
        __syncthreads();
        cur ^= 1;
    }

    if (qrow < S_) {
        const long rbase = ((long)split * 32 + b) * S_ + qrow;
        if (lg == 0) {
            Ml[rbase * 2] = m_run;
            Ml[rbase * 2 + 1] = l_run;
        }
        float* P = Pacc + rbase * 64;
        #pragma unroll
        for (int dt = 0; dt < 4; ++dt)
            *(float4v*)(P + dt * 16 + lg * 4) = acc[dt];
    }
}

// ---------------------------------------------------------------------------
// Split-K combine: log-sum-exp merge of 2 partials, qm multiply, 1/l, bf16 Om.
// Block = 4 rows x 64 lanes (lane = d).
// ---------------------------------------------------------------------------
__global__ __launch_bounds__(256) void combine_kernel(
    const float* __restrict__ Pacc, const float* __restrict__ Ml,
    const float* __restrict__ qm, ushort_t* __restrict__ Om)
{
    const int tid = threadIdx.x;
    const long row = (long)blockIdx.x * 4 + (tid >> 6);   // b*S + q
    const int lane = tid & 63;
    const int b = (int)(row / S_);
    const int q = (int)(row - (long)b * S_);

    const float2 ml0 = *(const float2*)(Ml + row * 2);
    const float2 ml1 = *(const float2*)(Ml + (row + 32L * S_) * 2);
    const float M = fmaxf(ml0.x, ml1.x);
    const float w0 = __expf(ml0.x - M);
    const float w1 = __expf(ml1.x - M);
    float l = fmaf(ml0.y, w0, ml1.y * w1);
    l = fmaxf(l, 1e-20f);

    const float a0 = Pacc[row * 64 + lane];
    const float a1 = Pacc[(row + 32L * S_) * 64 + lane];
    const float scale = qm[(b & 3) * S_ + q] / l;
    const float o = fmaf(a0, w0, a1 * w1) * scale;
    Om[((long)(b & 3) * S_ + q) * C_ + (b >> 2) * 64 + lane] = f2bf(o);
}

// ---------------------------------------------------------------------------
// LN pass 1: per-position mean and 1/(std+eps) from bf16 Om + residual
// ---------------------------------------------------------------------------
__global__ __launch_bounds__(256) void ln_stats_kernel(
    const ushort_t* __restrict__ Om, const ushort_t* __restrict__ qbf,
    float* __restrict__ stats)
{
    const int tid = threadIdx.x;
    const int w = tid >> 6, lane = tid & 63;
    const long p = blockIdx.x * 4 + w;
    const short8v ov = *(const short8v*)(Om + p * C_ + lane * 8);
    const short8v qv = *(const short8v*)(qbf + p * C_ + lane * 8);
    float sum = 0.f, ssq = 0.f;
    #pragma unroll
    for (int j = 0; j < 8; ++j) {
        const float v = bf2f(((const ushort_t*)&ov)[j]) + bf2f(((const ushort_t*)&qv)[j]);
        sum += v; ssq += v * v;
    }
    #pragma unroll
    for (int off = 32; off > 0; off >>= 1) {
        sum += __shfl_xor(sum, off, 64);
        ssq += __shfl_xor(ssq, off, 64);
    }
    if (lane == 0) {
        const float mean = sum * (1.f / 512.f);
        float var = (ssq - sum * mean) * (1.f / 511.f);
        var = var > 0.f ? var : 0.f;
        stats[p * 2] = mean;
        stats[p * 2 + 1] = 1.f / (sqrtf(var) + EPS_);
    }
}

// ---------------------------------------------------------------------------
// LN pass 2: normalize + gamma/beta, LDS-transposed, float4 writes
// ---------------------------------------------------------------------------
__global__ __launch_bounds__(256) void ln_write_kernel(
    const ushort_t* __restrict__ Om, const ushort_t* __restrict__ qbf,
    const float* __restrict__ stats, const float* __restrict__ gamma,
    const float* __restrict__ beta, float* __restrict__ out)
{
    __shared__ float Tl[64][197];
    const int nt = blockIdx.x;
    const int ct = blockIdx.y;
    const int tid = threadIdx.x;

    const int c0 = (tid & 15) * 4;               // constant per thread
    float g[4], bb[4];
    #pragma unroll
    for (int e = 0; e < 4; ++e) {
        g[e] = gamma[ct * 64 + c0 + e];
        bb[e] = beta[ct * 64 + c0 + e];
    }

    #pragma unroll
    for (int i = 0; i < 13; ++i) {
        const int idx = i * 256 + tid;
        if (idx < 3136) {
            const int hw = idx >> 4;
            const long p = (long)nt * HW_ + hw;
            const float mean = stats[p * 2];
            const float inv = stats[p * 2 + 1];
            const ushort4v ov = *(const ushort4v*)(Om + p * C_ + ct * 64 + c0);
            const ushort4v qv = *(const ushort4v*)(qbf + p * C_ + ct * 64 + c0);
            #pragma unroll
            for (int e = 0; e < 4; ++e) {
                const float xv = bf2f(ov[e]) + bf2f(qv[e]);
                Tl[c0 + e][hw] = g[e] * (xv - mean) * inv + bb[e];
            }
        }
    }
    __syncthreads();
    const long obase = ((long)nt * C_ + ct * 64) * HW_;
    #pragma unroll
    for (int i = 0; i < 13; ++i) {
        const int idx = i * 256 + tid;
        if (idx < 3136) {
            const int c = idx / 49;
            const int q4 = idx - c * 49;
            float4 v;
            v.x = Tl[c][q4 * 4 + 0];
            v.y = Tl[c][q4 * 4 + 1];
            v.z = Tl[c][q4 * 4 + 2];
            v.w = Tl[c][q4 * 4 + 3];
            *(float4*)(out + obase + c * HW_ + q4 * 4) = v;
        }
    }
}

extern "C" void kernel_launch(void* const* d_in, const int* in_sizes, int n_in,
                              void* d_out, int out_size, void* d_ws, size_t ws_size,
                              hipStream_t stream) {
    const float* q_in  = (const float*)d_in[0];
    const float* k_in  = (const float*)d_in[1];
    const float* v_in  = (const float*)d_in[2];
    const float* Wq    = (const float*)d_in[3];
    const float* bq    = (const float*)d_in[4];
    const float* Wk    = (const float*)d_in[5];
    const float* bk    = (const float*)d_in[6];
    const float* Wv    = (const float*)d_in[7];
    const float* bv    = (const float*)d_in[8];
    const float* gamma = (const float*)d_in[9];
    const float* beta  = (const float*)d_in[10];
    float* out = (float*)d_out;

    const size_t PC = (size_t)P_TOT * C_;            // 3,211,264
    ushort_t* qbf = (ushort_t*)d_ws;
    ushort_t* kbf = qbf + PC;
    ushort_t* vbf = kbf + PC;
    ushort_t* Qh  = vbf + PC;
    ushort_t* Kh  = Qh + PC;
    ushort_t* Vt  = Kh + PC;
    ushort_t* Om  = Vt + PC;                         // bf16 now
    float* Pacc  = (float*)(Om + PC);                // 2*32*1568*64
    float* Ml    = Pacc + 2L * 32 * S_ * 64;         // 2*32*1568*2
    float* stats = Ml + 2L * 32 * S_ * 2;
    float* qm    = stats + 2 * P_TOT;
    float* km    = qm + P_TOT;

    transpose_kernel<<<dim3(32, 8, 3), 256, 0, stream>>>(q_in, k_in, v_in, qbf, kbf, vbf);
    mask_kernel<<<P_TOT / 4, 256, 0, stream>>>(qbf, kbf, qm, km);
    proj_all<<<dim3(49, 8, 3), 256, 0, stream>>>(qbf, kbf, vbf, Wq, Wk, Wv,
                                                 bq, bk, bv, Qh, Kh, Vt);
    attn_kernel<<<dim3(800, 2), 256, 0, stream>>>(Qh, Kh, Vt, km, Pacc, Ml);
    combine_kernel<<<(32 * S_) / 4, 256, 0, stream>>>(Pacc, Ml, qm, Om);
    ln_stats_kernel<<<P_TOT / 4, 256, 0, stream>>>(Om, qbf, stats);
    ln_write_kernel<<<dim3(32, 8), 256, 0, stream>>>(Om, qbf, stats, gamma, beta, out);
}